// Round 1
// baseline (603.814 us; speedup 1.0000x reference)
//
#include <hip/hip_runtime.h>
#include <hip/hip_bf16.h>

// ---------------------------------------------------------------------------
// DAWN block on MI355X. Decomposition:
//   nx  = LN1(x)                                  [ln_kernel]
//   yqk = nx @ f_qk_flat^T  (K=1024, N=2048)      [gemm]
//   sq/sk = ws(yqk, fqk_w_*, rqk_w_*)             [ws_kernel]  (shared yqk!)
//   yv  = nx @ f_v_flat^T                         [gemm]
//   sv  = ws(yv, fv_w, rv_w)
//   Q/K/V = s* @ r_*_flat^T (K=2048, N=1024)      [gemm]
//   attn = causal flash attention (H=16, DH=64)   [fa_kernel]
//   x2(d_out) = attn @ W_O^T + x  (fp32 epilogue) [gemm EPI=1]
//   nx2 = LN2(x2); yk = nx2 @ f_know^T; sk2 = ws(yk,...)
//   out = sk2 @ r_know^T + x2  (fp32 epilogue)
// All GEMM B-operands pre-transposed to [N][K] bf16 so both MFMA fragments are
// k-contiguous b128 LDS reads.
// ---------------------------------------------------------------------------

typedef __bf16 bf16_t;
typedef __bf16 bf16x8 __attribute__((ext_vector_type(8)));
typedef float f32x4 __attribute__((ext_vector_type(4)));

#define B_DIM 2
#define S_LEN 2048
#define D_DIM 1024
#define H_NUM 16
#define DH 64
#define N_NEU 8
#define R_DIM 256
#define KR_DIM 128
#define ROWS (B_DIM * S_LEN)   // 4096

// ---------------------------------------------------------------------------
// Batched transpose-cast: in[b][I][J] f32 -> out[b][J][I] bf16.  block (32,8)
// ---------------------------------------------------------------------------
__global__ __launch_bounds__(256)
void tcast_kernel(const float* __restrict__ in, bf16_t* __restrict__ out, int I, int J)
{
    __shared__ float t[32][33];
    const int bJ = blockIdx.x * 32, bI = blockIdx.y * 32;
    const size_t boff = (size_t)blockIdx.z * I * J;
    const int tx = threadIdx.x, ty = threadIdx.y;
#pragma unroll
    for (int i = 0; i < 4; i++)
        t[ty * 4 + i][tx] = in[boff + (size_t)(bI + ty * 4 + i) * J + bJ + tx];
    __syncthreads();
#pragma unroll
    for (int i = 0; i < 4; i++)
        out[boff + (size_t)(bJ + ty * 4 + i) * I + bI + tx] = (bf16_t)t[tx][ty * 4 + i];
}

// plain cast fp32 -> bf16 (vectorized by 4)
__global__ __launch_bounds__(256)
void cast_kernel(const float* __restrict__ in, bf16_t* __restrict__ out, int n4)
{
    int i = blockIdx.x * 256 + threadIdx.x;
    if (i < n4) {
        float4 v = ((const float4*)in)[i];
        bf16_t* op = out + (size_t)i * 4;
        op[0] = (bf16_t)v.x; op[1] = (bf16_t)v.y; op[2] = (bf16_t)v.z; op[3] = (bf16_t)v.w;
    }
}

// ---------------------------------------------------------------------------
// LayerNorm over D=1024, one row per block (256 thr x 4 floats). fp32 in, bf16 out.
// ---------------------------------------------------------------------------
__global__ __launch_bounds__(256)
void ln_kernel(const float* __restrict__ x, const float* __restrict__ g,
               const float* __restrict__ beta, bf16_t* __restrict__ out)
{
    __shared__ float red[4];
    const int row = blockIdx.x;
    const int tid = threadIdx.x;
    float4 v = *(const float4*)&x[(size_t)row * D_DIM + tid * 4];

    float s = v.x + v.y + v.z + v.w;
#pragma unroll
    for (int o = 32; o; o >>= 1) s += __shfl_down(s, o);
    if ((tid & 63) == 0) red[tid >> 6] = s;
    __syncthreads();
    float mean = (red[0] + red[1] + red[2] + red[3]) * (1.f / D_DIM);
    __syncthreads();

    float dx = v.x - mean, dy = v.y - mean, dz = v.z - mean, dw = v.w - mean;
    float q = dx * dx + dy * dy + dz * dz + dw * dw;
#pragma unroll
    for (int o = 32; o; o >>= 1) q += __shfl_down(q, o);
    if ((tid & 63) == 0) red[tid >> 6] = q;
    __syncthreads();
    float var = (red[0] + red[1] + red[2] + red[3]) * (1.f / D_DIM);
    float rstd = rsqrtf(var + 1e-5f);

    float4 gv = *(const float4*)&g[tid * 4];
    float4 bv = *(const float4*)&beta[tid * 4];
    bf16_t* op = out + (size_t)row * D_DIM + tid * 4;
    op[0] = (bf16_t)(dx * rstd * gv.x + bv.x);
    op[1] = (bf16_t)(dy * rstd * gv.y + bv.y);
    op[2] = (bf16_t)(dz * rstd * gv.z + bv.z);
    op[3] = (bf16_t)(dw * rstd * gv.w + bv.w);
}

// ---------------------------------------------------------------------------
// Weighted-sum: h[r] = sum_n wf[n]*y[n*R+r]; s[n*R+r] = wr[n]*h[r].
// Rdim in {256,128}; block covers 256/Rdim rows.
// ---------------------------------------------------------------------------
__global__ __launch_bounds__(256)
void ws_kernel(const bf16_t* __restrict__ y, const float* __restrict__ wf,
               const float* __restrict__ wr, bf16_t* __restrict__ sout, int Rdim)
{
    const int rpb = 256 / Rdim;
    const int lr = threadIdx.x / Rdim;
    const int r  = threadIdx.x % Rdim;
    const int row = blockIdx.x * rpb + lr;
    const bf16_t* yrow = y + (size_t)row * N_NEU * Rdim;
    const float* wfp = wf + row * N_NEU;
    const float* wrp = wr + row * N_NEU;
    float acc = 0.f;
#pragma unroll
    for (int n = 0; n < N_NEU; n++) acc += wfp[n] * (float)yrow[n * Rdim + r];
    bf16_t* srow = sout + (size_t)row * N_NEU * Rdim;
#pragma unroll
    for (int n = 0; n < N_NEU; n++) srow[n * Rdim + r] = (bf16_t)(wrp[n] * acc);
}

// ---------------------------------------------------------------------------
// GEMM: C[M,N] = A[M,K] @ Bt[N,K]^T.  bf16 in, fp32 accumulate.
// 128x128 tile, BK=32, 4 waves each owning a 64x64 quadrant (4x4 16x16 frags).
// Reg-staged LDS with +8 pad (row stride 80B -> 2-way conflicts only).
// EPI=0: bf16 C.  EPI=1: fp32 C = acc + resid (resid may alias Cout).
// ---------------------------------------------------------------------------
template<int EPI>
__global__ __launch_bounds__(256)
void gemm_kernel(const bf16_t* __restrict__ A, const bf16_t* __restrict__ Bt,
                 void* Cout, const float* resid, int M, int N, int K)
{
    __shared__ bf16_t As[128][40];
    __shared__ bf16_t Bs[128][40];
    const int tid = threadIdx.x;
    const int l = tid & 63, w = tid >> 6;
    const int wr = w >> 1, wc = w & 1;
    const int m0 = blockIdx.y * 128, n0 = blockIdx.x * 128;

    const int srow = tid >> 1;
    const int scol = (tid & 1) * 16;
    const bf16_t* Ap = A  + (size_t)(m0 + srow) * K + scol;
    const bf16_t* Bp = Bt + (size_t)(n0 + srow) * K + scol;

    f32x4 acc[4][4];
    const f32x4 zero = {0.f, 0.f, 0.f, 0.f};
#pragma unroll
    for (int i = 0; i < 4; i++)
#pragma unroll
        for (int j = 0; j < 4; j++) acc[i][j] = zero;

    const int fr = l & 15;
    const int fk = (l >> 4) * 8;

    for (int k0 = 0; k0 < K; k0 += 32) {
        uint4 a0 = *(const uint4*)(Ap + k0);
        uint4 a1 = *(const uint4*)(Ap + k0 + 8);
        uint4 b0 = *(const uint4*)(Bp + k0);
        uint4 b1 = *(const uint4*)(Bp + k0 + 8);
        __syncthreads();
        *(uint4*)&As[srow][scol]     = a0;
        *(uint4*)&As[srow][scol + 8] = a1;
        *(uint4*)&Bs[srow][scol]     = b0;
        *(uint4*)&Bs[srow][scol + 8] = b1;
        __syncthreads();

        bf16x8 af[4], bv[4];
#pragma unroll
        for (int i = 0; i < 4; i++) af[i] = *(const bf16x8*)&As[wr * 64 + i * 16 + fr][fk];
#pragma unroll
        for (int i = 0; i < 4; i++) bv[i] = *(const bf16x8*)&Bs[wc * 64 + i * 16 + fr][fk];
#pragma unroll
        for (int mi = 0; mi < 4; mi++)
#pragma unroll
            for (int ni = 0; ni < 4; ni++)
                acc[mi][ni] = __builtin_amdgcn_mfma_f32_16x16x32_bf16(af[mi], bv[ni], acc[mi][ni], 0, 0, 0);
    }

    const int orow = (l >> 4) * 4;
    const int ocol = l & 15;
#pragma unroll
    for (int mi = 0; mi < 4; mi++)
#pragma unroll
        for (int ni = 0; ni < 4; ni++)
#pragma unroll
            for (int j = 0; j < 4; j++) {
                int row = m0 + wr * 64 + mi * 16 + orow + j;
                int col = n0 + wc * 64 + ni * 16 + ocol;
                size_t idx = (size_t)row * N + col;
                if constexpr (EPI == 0) {
                    ((bf16_t*)Cout)[idx] = (bf16_t)acc[mi][ni][j];
                } else {
                    ((float*)Cout)[idx] = acc[mi][ni][j] + resid[idx];
                }
            }
}

// ---------------------------------------------------------------------------
// Causal flash attention.  Layout: Q/K/V/O are [B*S][1024], head h = cols h*64..+64.
// Grid (S/64, B*H); 256 thr = 4 waves; wave w owns q rows q0+w*16..+16.
// K staged [32][72] (row-major, padded); V staged transposed [64][40];
// P transposed to A-layout via per-wave LDS bounce Ps[16][40].
// ---------------------------------------------------------------------------
__global__ __launch_bounds__(256)
void fa_kernel(const bf16_t* __restrict__ Q, const bf16_t* __restrict__ K,
               const bf16_t* __restrict__ V, bf16_t* __restrict__ O)
{
    __shared__ bf16_t Ks[32][72];
    __shared__ bf16_t Vs[64][40];
    __shared__ bf16_t Ps[4][16][40];

    const int tid = threadIdx.x;
    const int l = tid & 63, w = tid >> 6;
    const int bh = blockIdx.y;
    const int b = bh >> 4, h = bh & 15;
    const int q0 = blockIdx.x * 64;

    const bf16_t* Qp = Q + (size_t)b * S_LEN * D_DIM + h * DH;
    const bf16_t* Kp = K + (size_t)b * S_LEN * D_DIM + h * DH;
    const bf16_t* Vp = V + (size_t)b * S_LEN * D_DIM + h * DH;

    const int fr = l & 15, fg = l >> 4, fk = fg * 8;

    // Q fragments: lane holds Q[q0+w*16+fr][fk..fk+7] and [+32]
    const int qrow = q0 + w * 16 + fr;
    const bf16x8 qf0 = *(const bf16x8*)(Qp + (size_t)qrow * D_DIM + fk);
    const bf16x8 qf1 = *(const bf16x8*)(Qp + (size_t)qrow * D_DIM + 32 + fk);

    const f32x4 zero = {0.f, 0.f, 0.f, 0.f};
    f32x4 o[4];
#pragma unroll
    for (int c = 0; c < 4; c++) o[c] = zero;
    float m_r[4], l_r[4];
#pragma unroll
    for (int j = 0; j < 4; j++) { m_r[j] = -1e30f; l_r[j] = 0.f; }

    const int s_kr = tid >> 3;        // 0..31 key row
    const int s_c  = (tid & 7) * 8;   // dh chunk 0..56

    const int kmax = q0 + 64;
    const int wq_hi = q0 + w * 16 + 15;

    for (int k0 = 0; k0 < kmax; k0 += 32) {
        __syncthreads();
        // stage K tile [32 keys][64 dh]
        uint4 kv = *(const uint4*)(Kp + (size_t)(k0 + s_kr) * D_DIM + s_c);
        *(uint4*)&Ks[s_kr][s_c] = kv;
        // stage V transposed: Vs[dh][key]
        uint4 vv = *(const uint4*)(Vp + (size_t)(k0 + s_kr) * D_DIM + s_c);
        const bf16_t* ve = (const bf16_t*)&vv;
#pragma unroll
        for (int i = 0; i < 8; i++) Vs[s_c + i][s_kr] = ve[i];
        __syncthreads();

        if (k0 > wq_hi) continue;   // whole tile above this wave's diagonal

        float pj[2][4];
#pragma unroll
        for (int s = 0; s < 2; s++) {
            bf16x8 kf0 = *(const bf16x8*)&Ks[s * 16 + fr][fk];
            bf16x8 kf1 = *(const bf16x8*)&Ks[s * 16 + fr][32 + fk];
            f32x4 sc = zero;
            sc = __builtin_amdgcn_mfma_f32_16x16x32_bf16(qf0, kf0, sc, 0, 0, 0);
            sc = __builtin_amdgcn_mfma_f32_16x16x32_bf16(qf1, kf1, sc, 0, 0, 0);
            const int keyg = k0 + s * 16 + fr;          // D col
#pragma unroll
            for (int j = 0; j < 4; j++) {
                const int qg = q0 + w * 16 + fg * 4 + j; // D row
                float v = sc[j] * 0.125f;                // 1/sqrt(64)
                pj[s][j] = (keyg <= qg) ? v : -1e30f;
            }
        }
        // online softmax per row j (row = 16 lanes sharing fg)
#pragma unroll
        for (int j = 0; j < 4; j++) {
            float rmax = fmaxf(pj[0][j], pj[1][j]);
#pragma unroll
            for (int d = 1; d < 16; d <<= 1) rmax = fmaxf(rmax, __shfl_xor(rmax, d));
            float mnew = fmaxf(m_r[j], rmax);
            float scale = __expf(m_r[j] - mnew);
            float p0 = __expf(pj[0][j] - mnew);
            float p1 = __expf(pj[1][j] - mnew);
            float rsum = p0 + p1;
#pragma unroll
            for (int d = 1; d < 16; d <<= 1) rsum += __shfl_xor(rsum, d);
            l_r[j] = l_r[j] * scale + rsum;
            m_r[j] = mnew;
#pragma unroll
            for (int c = 0; c < 4; c++) o[c][j] *= scale;
            pj[0][j] = p0; pj[1][j] = p1;
        }
        // transpose P (D-layout) -> A-layout via per-wave LDS
#pragma unroll
        for (int s = 0; s < 2; s++)
#pragma unroll
            for (int j = 0; j < 4; j++)
                Ps[w][fg * 4 + j][s * 16 + fr] = (bf16_t)pj[s][j];
        bf16x8 pf = *(const bf16x8*)&Ps[w][fr][fk];
        // PV: o[q][c*16+col] += P[16x32] @ V[32 x 16-chunk]
#pragma unroll
        for (int c = 0; c < 4; c++) {
            bf16x8 vf = *(const bf16x8*)&Vs[c * 16 + fr][fk];
            o[c] = __builtin_amdgcn_mfma_f32_16x16x32_bf16(pf, vf, o[c], 0, 0, 0);
        }
    }

#pragma unroll
    for (int j = 0; j < 4; j++) {
        const float inv = 1.f / l_r[j];
        const int q = q0 + w * 16 + fg * 4 + j;
        bf16_t* op = O + (size_t)(b * S_LEN + q) * D_DIM + h * DH;
#pragma unroll
        for (int c = 0; c < 4; c++)
            op[c * 16 + fr] = (bf16_t)(o[c][j] * inv);
    }
}

// ---------------------------------------------------------------------------
extern "C" void kernel_launch(void* const* d_in, const int* in_sizes, int n_in,
                              void* d_out, int out_size, void* d_ws, size_t ws_size,
                              hipStream_t stream)
{
    const float* x      = (const float*)d_in[0];
    const float* fqk_wQ = (const float*)d_in[1];
    const float* fqk_wK = (const float*)d_in[2];
    const float* fv_w   = (const float*)d_in[3];
    const float* rqk_wQ = (const float*)d_in[4];
    const float* rqk_wK = (const float*)d_in[5];
    const float* rv_w   = (const float*)d_in[6];
    const float* fkn_w  = (const float*)d_in[7];
    const float* rkn_w  = (const float*)d_in[8];
    const float* f_qk   = (const float*)d_in[9];
    const float* f_v    = (const float*)d_in[10];
    const float* r_qk   = (const float*)d_in[11];
    const float* r_v    = (const float*)d_in[12];
    const float* f_know = (const float*)d_in[13];
    const float* r_know = (const float*)d_in[14];
    const float* W_O    = (const float*)d_in[15];
    const float* ln1g   = (const float*)d_in[16];
    const float* ln1b   = (const float*)d_in[17];
    const float* ln2g   = (const float*)d_in[18];
    const float* ln2b   = (const float*)d_in[19];
    float* out_f = (float*)d_out;

    // ---- workspace layout (bf16 buffers; peak ~94 MB, slots reused) ----
    char* ws = (char*)d_ws;
    size_t off = 0;
    auto alloc = [&](size_t bytes) -> void* {
        void* p = ws + off; off += (bytes + 255) & ~(size_t)255; return p;
    };
    bf16_t* fqkT  = (bf16_t*)alloc((size_t)2048 * 1024 * 2);  // [n*R+r][d]
    bf16_t* fvT   = (bf16_t*)alloc((size_t)2048 * 1024 * 2);
    bf16_t* fknT  = (bf16_t*)alloc((size_t)1024 * 1024 * 2);  // [n*KR+r][d]
    bf16_t* rqkT  = (bf16_t*)alloc((size_t)1024 * 2048 * 2);  // [d][n*R+r]
    bf16_t* rvT   = (bf16_t*)alloc((size_t)1024 * 2048 * 2);
    bf16_t* rknT  = (bf16_t*)alloc((size_t)1024 * 1024 * 2);  // [d][n*KR+r]
    bf16_t* woB   = (bf16_t*)alloc((size_t)1024 * 1024 * 2);  // W_O as-is = Bt
    bf16_t* buf_nx = (bf16_t*)alloc((size_t)ROWS * 1024 * 2); // nx / nx2
    bf16_t* buf_y  = (bf16_t*)alloc((size_t)ROWS * 2048 * 2); // yqk / yv / Qb / yk
    bf16_t* buf_s1 = (bf16_t*)alloc((size_t)ROWS * 2048 * 2); // sq / Kb / sk2
    bf16_t* buf_s2 = (bf16_t*)alloc((size_t)ROWS * 2048 * 2); // sk / Vb
    bf16_t* buf_s3 = (bf16_t*)alloc((size_t)ROWS * 2048 * 2); // sv / attn
    (void)ws_size; (void)in_sizes; (void)n_in; (void)out_size;

    const dim3 blk256(256), blkT(32, 8);

    // ---- weight conversion (bf16, transposed to [N][K]) ----
    tcast_kernel<<<dim3(R_DIM / 32, D_DIM / 32, N_NEU), blkT, 0, stream>>>(f_qk, fqkT, D_DIM, R_DIM);
    tcast_kernel<<<dim3(R_DIM / 32, D_DIM / 32, N_NEU), blkT, 0, stream>>>(f_v, fvT, D_DIM, R_DIM);
    tcast_kernel<<<dim3(KR_DIM / 32, D_DIM / 32, N_NEU), blkT, 0, stream>>>(f_know, fknT, D_DIM, KR_DIM);
    tcast_kernel<<<dim3(D_DIM / 32, 2048 / 32, 1), blkT, 0, stream>>>(r_qk, rqkT, 2048, D_DIM);
    tcast_kernel<<<dim3(D_DIM / 32, 2048 / 32, 1), blkT, 0, stream>>>(r_v, rvT, 2048, D_DIM);
    tcast_kernel<<<dim3(D_DIM / 32, 1024 / 32, 1), blkT, 0, stream>>>(r_know, rknT, 1024, D_DIM);
    cast_kernel<<<dim3((1024 * 1024 / 4 + 255) / 256), blk256, 0, stream>>>(W_O, woB, 1024 * 1024 / 4);

    // ---- LN1 ----
    ln_kernel<<<dim3(ROWS), blk256, 0, stream>>>(x, ln1g, ln1b, buf_nx);

    // ---- feature qk: yqk = nx @ fqkT^T ; sq,sk ----
    gemm_kernel<0><<<dim3(2048 / 128, ROWS / 128), blk256, 0, stream>>>(buf_nx, fqkT, buf_y, nullptr, ROWS, 2048, 1024);
    ws_kernel<<<dim3(ROWS), blk256, 0, stream>>>(buf_y, fqk_wQ, rqk_wQ, buf_s1, R_DIM);
    ws_kernel<<<dim3(ROWS), blk256, 0, stream>>>(buf_y, fqk_wK, rqk_wK, buf_s2, R_DIM);

    // ---- feature v: yv = nx @ fvT^T ; sv ----
    gemm_kernel<0><<<dim3(2048 / 128, ROWS / 128), blk256, 0, stream>>>(buf_nx, fvT, buf_y, nullptr, ROWS, 2048, 1024);
    ws_kernel<<<dim3(ROWS), blk256, 0, stream>>>(buf_y, fv_w, rv_w, buf_s3, R_DIM);

    // ---- restores: Q=sq@rqkT^T (into buf_y), K=sk@rqkT^T (into buf_s1), V=sv@rvT^T (into buf_s2) ----
    gemm_kernel<0><<<dim3(1024 / 128, ROWS / 128), blk256, 0, stream>>>(buf_s1, rqkT, buf_y, nullptr, ROWS, 1024, 2048);
    gemm_kernel<0><<<dim3(1024 / 128, ROWS / 128), blk256, 0, stream>>>(buf_s2, rqkT, buf_s1, nullptr, ROWS, 1024, 2048);
    gemm_kernel<0><<<dim3(1024 / 128, ROWS / 128), blk256, 0, stream>>>(buf_s3, rvT, buf_s2, nullptr, ROWS, 1024, 2048);

    // ---- attention: attn (into buf_s3) ----
    fa_kernel<<<dim3(S_LEN / 64, B_DIM * H_NUM), blk256, 0, stream>>>(buf_y, buf_s1, buf_s2, buf_s3);

    // ---- x2 = attn @ W_O^T + x  -> d_out (fp32) ----
    gemm_kernel<1><<<dim3(1024 / 128, ROWS / 128), blk256, 0, stream>>>(buf_s3, woB, d_out, x, ROWS, 1024, 1024);

    // ---- LN2, knowledge path ----
    ln_kernel<<<dim3(ROWS), blk256, 0, stream>>>(out_f, ln2g, ln2b, buf_nx);
    gemm_kernel<0><<<dim3(1024 / 128, ROWS / 128), blk256, 0, stream>>>(buf_nx, fknT, buf_y, nullptr, ROWS, 1024, 1024);
    ws_kernel<<<dim3(ROWS / 2), blk256, 0, stream>>>(buf_y, fkn_w, rkn_w, buf_s1, KR_DIM);

    // ---- out = sk2 @ rknT^T + x2 -> d_out (fp32, resid aliases Cout) ----
    gemm_kernel<1><<<dim3(1024 / 128, ROWS / 128), blk256, 0, stream>>>(buf_s1, rknT, d_out, out_f, ROWS, 1024, 1024);
}

// Round 2
// 506.438 us; speedup vs baseline: 1.1923x; 1.1923x over previous
//
#include <hip/hip_runtime.h>
#include <hip/hip_bf16.h>

// ---------------------------------------------------------------------------
// DAWN block on MI355X.  Round 2: m97-style global_load_lds GEMM + rebuilt
// flash attention (pre-transposed V, 128-q tile, KVBLK=64).
// ---------------------------------------------------------------------------

typedef __bf16 bf16_t;
typedef __bf16 bf16x8 __attribute__((ext_vector_type(8)));
typedef float f32x4 __attribute__((ext_vector_type(4)));

#define B_DIM 2
#define S_LEN 2048
#define D_DIM 1024
#define H_NUM 16
#define DH 64
#define N_NEU 8
#define R_DIM 256
#define KR_DIM 128
#define ROWS (B_DIM * S_LEN)   // 4096

static __device__ __forceinline__ void gl_lds16(const void* g, void* l)
{
    __builtin_amdgcn_global_load_lds(
        (__attribute__((address_space(1))) void*)(g),
        (__attribute__((address_space(3))) void*)(l), 16, 0, 0);
}

// ---------------------------------------------------------------------------
// Batched transpose-cast: in[z][I][J] f32 -> out[z][J][I] bf16.  block (32,8)
// ---------------------------------------------------------------------------
__global__ __launch_bounds__(256)
void tcast_kernel(const float* __restrict__ in, bf16_t* __restrict__ out, int I, int J)
{
    __shared__ float t[32][33];
    const int bJ = blockIdx.x * 32, bI = blockIdx.y * 32;
    const size_t boff = (size_t)blockIdx.z * I * J;
    const int tx = threadIdx.x, ty = threadIdx.y;
#pragma unroll
    for (int i = 0; i < 4; i++)
        t[ty * 4 + i][tx] = in[boff + (size_t)(bI + ty * 4 + i) * J + bJ + tx];
    __syncthreads();
#pragma unroll
    for (int i = 0; i < 4; i++)
        out[boff + (size_t)(bJ + ty * 4 + i) * I + bI + tx] = (bf16_t)t[tx][ty * 4 + i];
}

// bf16 transpose: in[z][I][J] -> out[z][J][I].  block (32,8)
__global__ __launch_bounds__(256)
void tbf_kernel(const bf16_t* __restrict__ in, bf16_t* __restrict__ out, int I, int J)
{
    __shared__ bf16_t t[32][33];
    const int bJ = blockIdx.x * 32, bI = blockIdx.y * 32;
    const size_t boff = (size_t)blockIdx.z * I * J;
    const int tx = threadIdx.x, ty = threadIdx.y;
#pragma unroll
    for (int i = 0; i < 4; i++)
        t[ty * 4 + i][tx] = in[boff + (size_t)(bI + ty * 4 + i) * J + bJ + tx];
    __syncthreads();
#pragma unroll
    for (int i = 0; i < 4; i++)
        out[boff + (size_t)(bJ + ty * 4 + i) * I + bI + tx] = t[tx][ty * 4 + i];
}

// plain cast fp32 -> bf16 (vectorized by 4)
__global__ __launch_bounds__(256)
void cast_kernel(const float* __restrict__ in, bf16_t* __restrict__ out, int n4)
{
    int i = blockIdx.x * 256 + threadIdx.x;
    if (i < n4) {
        float4 v = ((const float4*)in)[i];
        bf16_t* op = out + (size_t)i * 4;
        op[0] = (bf16_t)v.x; op[1] = (bf16_t)v.y; op[2] = (bf16_t)v.z; op[3] = (bf16_t)v.w;
    }
}

// ---------------------------------------------------------------------------
// LayerNorm over D=1024, one row per block. fp32 in, bf16 out.
// ---------------------------------------------------------------------------
__global__ __launch_bounds__(256)
void ln_kernel(const float* __restrict__ x, const float* __restrict__ g,
               const float* __restrict__ beta, bf16_t* __restrict__ out)
{
    __shared__ float red[4];
    const int row = blockIdx.x;
    const int tid = threadIdx.x;
    float4 v = *(const float4*)&x[(size_t)row * D_DIM + tid * 4];

    float s = v.x + v.y + v.z + v.w;
#pragma unroll
    for (int o = 32; o; o >>= 1) s += __shfl_down(s, o);
    if ((tid & 63) == 0) red[tid >> 6] = s;
    __syncthreads();
    float mean = (red[0] + red[1] + red[2] + red[3]) * (1.f / D_DIM);
    __syncthreads();

    float dx = v.x - mean, dy = v.y - mean, dz = v.z - mean, dw = v.w - mean;
    float q = dx * dx + dy * dy + dz * dz + dw * dw;
#pragma unroll
    for (int o = 32; o; o >>= 1) q += __shfl_down(q, o);
    if ((tid & 63) == 0) red[tid >> 6] = q;
    __syncthreads();
    float var = (red[0] + red[1] + red[2] + red[3]) * (1.f / D_DIM);
    float rstd = rsqrtf(var + 1e-5f);

    float4 gv = *(const float4*)&g[tid * 4];
    float4 bv = *(const float4*)&beta[tid * 4];
    bf16_t* op = out + (size_t)row * D_DIM + tid * 4;
    op[0] = (bf16_t)(dx * rstd * gv.x + bv.x);
    op[1] = (bf16_t)(dy * rstd * gv.y + bv.y);
    op[2] = (bf16_t)(dz * rstd * gv.z + bv.z);
    op[3] = (bf16_t)(dw * rstd * gv.w + bv.w);
}

// ---------------------------------------------------------------------------
// Weighted-sum: h[r] = sum_n wf[n]*y[n*R+r]; s[n*R+r] = wr[n]*h[r].
// ---------------------------------------------------------------------------
__global__ __launch_bounds__(256)
void ws_kernel(const bf16_t* __restrict__ y, const float* __restrict__ wf,
               const float* __restrict__ wr, bf16_t* __restrict__ sout, int Rdim)
{
    const int rpb = 256 / Rdim;
    const int lr = threadIdx.x / Rdim;
    const int r  = threadIdx.x % Rdim;
    const int row = blockIdx.x * rpb + lr;
    const bf16_t* yrow = y + (size_t)row * N_NEU * Rdim;
    const float* wfp = wf + row * N_NEU;
    const float* wrp = wr + row * N_NEU;
    float acc = 0.f;
#pragma unroll
    for (int n = 0; n < N_NEU; n++) acc += wfp[n] * (float)yrow[n * Rdim + r];
    bf16_t* srow = sout + (size_t)row * N_NEU * Rdim;
#pragma unroll
    for (int n = 0; n < N_NEU; n++) srow[n * Rdim + r] = (bf16_t)(wrp[n] * acc);
}

// ---------------------------------------------------------------------------
// GEMM (m97 structure): C[M,N] = A[M,K] @ Bt[N,K]^T.  128x128 tile, BK=32,
// global_load_lds width=16 into LINEAR LDS [128][32], 2 barriers/K-step.
// Wave w stages 16-row chunks {2w,2w+1} of both A and B tiles.
// EPI=0: bf16 C.  EPI=1: fp32 C = acc + resid (resid may alias Cout).
// ---------------------------------------------------------------------------
template<int EPI>
__global__ __launch_bounds__(256)
void gemm_kernel(const bf16_t* __restrict__ A, const bf16_t* __restrict__ Bt,
                 void* Cout, const float* resid, int M, int N, int K)
{
    __shared__ bf16_t As[128][32];
    __shared__ bf16_t Bs[128][32];
    const int tid = threadIdx.x;
    const int l = tid & 63, w = tid >> 6;
    const int wr = w >> 1, wc = w & 1;
    const int m0 = blockIdx.y * 128, n0 = blockIdx.x * 128;

    // staging addresses: chunk c covers rows 16c..16c+15; lane l -> row 16c+l/4,
    // col elems (l&3)*8.  LDS dest = tile_base + c*1024 + lane*16 (linear).
    const int srow = l >> 2;
    const int scol = (l & 3) * 8;
    const bf16_t* Ag0 = A  + (size_t)(m0 + w * 32 + srow) * K + scol;
    const bf16_t* Ag1 = Ag0 + (size_t)16 * K;
    const bf16_t* Bg0 = Bt + (size_t)(n0 + w * 32 + srow) * K + scol;
    const bf16_t* Bg1 = Bg0 + (size_t)16 * K;
    char* Asb = (char*)&As[0][0] + w * 2048;
    char* Bsb = (char*)&Bs[0][0] + w * 2048;

    f32x4 acc[4][4];
    const f32x4 zero = {0.f, 0.f, 0.f, 0.f};
#pragma unroll
    for (int i = 0; i < 4; i++)
#pragma unroll
        for (int j = 0; j < 4; j++) acc[i][j] = zero;

    const int fr = l & 15;
    const int fk = (l >> 4) * 8;

    for (int k0 = 0; k0 < K; k0 += 32) {
        gl_lds16(Ag0 + k0, Asb);
        gl_lds16(Ag1 + k0, Asb + 1024);
        gl_lds16(Bg0 + k0, Bsb);
        gl_lds16(Bg1 + k0, Bsb + 1024);
        __syncthreads();   // drains vmcnt; staged data visible

        bf16x8 af[4], bv[4];
#pragma unroll
        for (int i = 0; i < 4; i++) af[i] = *(const bf16x8*)&As[wr * 64 + i * 16 + fr][fk];
#pragma unroll
        for (int i = 0; i < 4; i++) bv[i] = *(const bf16x8*)&Bs[wc * 64 + i * 16 + fr][fk];
#pragma unroll
        for (int mi = 0; mi < 4; mi++)
#pragma unroll
            for (int ni = 0; ni < 4; ni++)
                acc[mi][ni] = __builtin_amdgcn_mfma_f32_16x16x32_bf16(af[mi], bv[ni], acc[mi][ni], 0, 0, 0);
        __syncthreads();   // reads done before next-stage overwrite
    }

    const int orow = (l >> 4) * 4;
    const int ocol = l & 15;
#pragma unroll
    for (int mi = 0; mi < 4; mi++)
#pragma unroll
        for (int ni = 0; ni < 4; ni++)
#pragma unroll
            for (int j = 0; j < 4; j++) {
                int row = m0 + wr * 64 + mi * 16 + orow + j;
                int col = n0 + wc * 64 + ni * 16 + ocol;
                size_t idx = (size_t)row * N + col;
                if constexpr (EPI == 0) {
                    ((bf16_t*)Cout)[idx] = (bf16_t)acc[mi][ni][j];
                } else {
                    ((float*)Cout)[idx] = acc[mi][ni][j] + resid[idx];
                }
            }
}

// ---------------------------------------------------------------------------
// Causal flash attention.  Q/K/O: [B*S][1024] bf16 (head h = cols h*64..+64).
// Vt: [B][1024][2048] bf16 (pre-transposed V).
// Grid (S/128, B*H); 256 thr = 4 waves; wave w owns q rows q0+w*32..+32.
// KVBLK=64.  Ks[64][72] keys row-major; Vs[64][72] = Vt tile (dcol major);
// P transposed to A-layout via per-wave Ps[32][72].
// ---------------------------------------------------------------------------
__global__ __launch_bounds__(256)
void fa_kernel(const bf16_t* __restrict__ Q, const bf16_t* __restrict__ K,
               const bf16_t* __restrict__ Vt, bf16_t* __restrict__ O)
{
    __shared__ bf16_t Ks[64][72];
    __shared__ bf16_t Vs[64][72];
    __shared__ bf16_t Ps[4][32][72];

    const int tid = threadIdx.x;
    const int l = tid & 63, w = tid >> 6;
    const int bh = blockIdx.y;
    const int b = bh >> 4, h = bh & 15;
    const int q0 = ((int)gridDim.x - 1 - (int)blockIdx.x) * 128;  // heavy blocks first

    const bf16_t* Qp = Q + (size_t)b * S_LEN * D_DIM + h * DH;
    const bf16_t* Kp = K + (size_t)b * S_LEN * D_DIM + h * DH;
    const bf16_t* Vp = Vt + (size_t)b * D_DIM * S_LEN + (size_t)h * DH * S_LEN;

    const int fr = l & 15, fg = l >> 4, fk = fg * 8;

    // Q fragments (2 row-frags x 2 k-steps)
    bf16x8 qf[2][2];
#pragma unroll
    for (int mi = 0; mi < 2; mi++)
#pragma unroll
        for (int ks = 0; ks < 2; ks++)
            qf[mi][ks] = *(const bf16x8*)(Qp + (size_t)(q0 + w * 32 + mi * 16 + fr) * D_DIM + ks * 32 + fk);

    const f32x4 zero = {0.f, 0.f, 0.f, 0.f};
    f32x4 o[2][4];
    float m_r[2][4], l_r[2][4];
#pragma unroll
    for (int mi = 0; mi < 2; mi++)
#pragma unroll
        for (int j = 0; j < 4; j++) { o[mi][j] = zero; m_r[mi][j] = -1e30f; l_r[mi][j] = 0.f; }

    const int srow = tid >> 2;        // 0..63
    const int scol = (tid & 3) * 16;  // 0,16,32,48

    const int kmax = q0 + 128;
    const int wq_hi = q0 + w * 32 + 31;

    for (int k0 = 0; k0 < kmax; k0 += 64) {
        // issue global loads early (latency overlaps the barrier)
        uint4 kva = *(const uint4*)(Kp + (size_t)(k0 + srow) * D_DIM + scol);
        uint4 kvb = *(const uint4*)(Kp + (size_t)(k0 + srow) * D_DIM + scol + 8);
        uint4 vva = *(const uint4*)(Vp + (size_t)srow * S_LEN + k0 + scol);
        uint4 vvb = *(const uint4*)(Vp + (size_t)srow * S_LEN + k0 + scol + 8);
        __syncthreads();              // previous iteration's reads complete
        *(uint4*)&Ks[srow][scol]     = kva;
        *(uint4*)&Ks[srow][scol + 8] = kvb;
        *(uint4*)&Vs[srow][scol]     = vva;
        *(uint4*)&Vs[srow][scol + 8] = vvb;
        __syncthreads();

        if (k0 > wq_hi) continue;     // tile entirely above this wave's diagonal

        // ---- QK^T:  sc[mi][ni] = Q(32 rows) x K(64 keys) ----
        f32x4 sc[2][4];
#pragma unroll
        for (int mi = 0; mi < 2; mi++)
#pragma unroll
            for (int ni = 0; ni < 4; ni++) sc[mi][ni] = zero;
#pragma unroll
        for (int ks = 0; ks < 2; ks++) {
            bf16x8 kf[4];
#pragma unroll
            for (int ni = 0; ni < 4; ni++)
                kf[ni] = *(const bf16x8*)&Ks[ni * 16 + fr][ks * 32 + fk];
#pragma unroll
            for (int mi = 0; mi < 2; mi++)
#pragma unroll
                for (int ni = 0; ni < 4; ni++)
                    sc[mi][ni] = __builtin_amdgcn_mfma_f32_16x16x32_bf16(qf[mi][ks], kf[ni], sc[mi][ni], 0, 0, 0);
        }

        // ---- scale + causal mask ----
        float p[2][4][4];
#pragma unroll
        for (int mi = 0; mi < 2; mi++)
#pragma unroll
            for (int ni = 0; ni < 4; ni++) {
                const int key = k0 + ni * 16 + fr;
#pragma unroll
                for (int j = 0; j < 4; j++) {
                    const int qg = q0 + w * 32 + mi * 16 + fg * 4 + j;
                    p[mi][ni][j] = (key <= qg) ? sc[mi][ni][j] * 0.125f : -1e30f;
                }
            }

        // ---- online softmax (row = (mi,j), 16 lanes sharing fg hold the cols) ----
#pragma unroll
        for (int mi = 0; mi < 2; mi++)
#pragma unroll
            for (int j = 0; j < 4; j++) {
                float rmax = fmaxf(fmaxf(p[mi][0][j], p[mi][1][j]), fmaxf(p[mi][2][j], p[mi][3][j]));
#pragma unroll
                for (int d = 1; d < 16; d <<= 1) rmax = fmaxf(rmax, __shfl_xor(rmax, d));
                float mnew = fmaxf(m_r[mi][j], rmax);
                float scale = __expf(m_r[mi][j] - mnew);
                float rsum = 0.f;
#pragma unroll
                for (int ni = 0; ni < 4; ni++) {
                    float e = __expf(p[mi][ni][j] - mnew);
                    p[mi][ni][j] = e; rsum += e;
                }
#pragma unroll
                for (int d = 1; d < 16; d <<= 1) rsum += __shfl_xor(rsum, d);
                l_r[mi][j] = l_r[mi][j] * scale + rsum;
                m_r[mi][j] = mnew;
#pragma unroll
                for (int nc = 0; nc < 4; nc++) o[mi][nc][j] *= scale;
            }

        // ---- P -> A-layout via per-wave LDS (same-wave DS ordering, no barrier) ----
#pragma unroll
        for (int mi = 0; mi < 2; mi++)
#pragma unroll
            for (int ni = 0; ni < 4; ni++)
#pragma unroll
                for (int j = 0; j < 4; j++)
                    Ps[w][mi * 16 + fg * 4 + j][ni * 16 + fr] = (bf16_t)p[mi][ni][j];

        // ---- PV:  o[mi][nc] += P[32 x 64] @ Vt[64-dcol x 64-key]^T ----
#pragma unroll
        for (int ks = 0; ks < 2; ks++) {
            bf16x8 pa[2];
#pragma unroll
            for (int mi = 0; mi < 2; mi++)
                pa[mi] = *(const bf16x8*)&Ps[w][mi * 16 + fr][ks * 32 + fk];
#pragma unroll
            for (int nc = 0; nc < 4; nc++) {
                bf16x8 vf = *(const bf16x8*)&Vs[nc * 16 + fr][ks * 32 + fk];
#pragma unroll
                for (int mi = 0; mi < 2; mi++)
                    o[mi][nc] = __builtin_amdgcn_mfma_f32_16x16x32_bf16(pa[mi], vf, o[mi][nc], 0, 0, 0);
            }
        }
    }

    // ---- epilogue ----
#pragma unroll
    for (int mi = 0; mi < 2; mi++)
#pragma unroll
        for (int j = 0; j < 4; j++) {
            const float inv = 1.f / l_r[mi][j];
            const int q = q0 + w * 32 + mi * 16 + fg * 4 + j;
            bf16_t* op = O + (size_t)(b * S_LEN + q) * D_DIM + h * DH;
#pragma unroll
            for (int nc = 0; nc < 4; nc++)
                op[nc * 16 + fr] = (bf16_t)(o[mi][nc][j] * inv);
        }
}

// ---------------------------------------------------------------------------
extern "C" void kernel_launch(void* const* d_in, const int* in_sizes, int n_in,
                              void* d_out, int out_size, void* d_ws, size_t ws_size,
                              hipStream_t stream)
{
    const float* x      = (const float*)d_in[0];
    const float* fqk_wQ = (const float*)d_in[1];
    const float* fqk_wK = (const float*)d_in[2];
    const float* fv_w   = (const float*)d_in[3];
    const float* rqk_wQ = (const float*)d_in[4];
    const float* rqk_wK = (const float*)d_in[5];
    const float* rv_w   = (const float*)d_in[6];
    const float* fkn_w  = (const float*)d_in[7];
    const float* rkn_w  = (const float*)d_in[8];
    const float* f_qk   = (const float*)d_in[9];
    const float* f_v    = (const float*)d_in[10];
    const float* r_qk   = (const float*)d_in[11];
    const float* r_v    = (const float*)d_in[12];
    const float* f_know = (const float*)d_in[13];
    const float* r_know = (const float*)d_in[14];
    const float* W_O    = (const float*)d_in[15];
    const float* ln1g   = (const float*)d_in[16];
    const float* ln1b   = (const float*)d_in[17];
    const float* ln2g   = (const float*)d_in[18];
    const float* ln2b   = (const float*)d_in[19];
    float* out_f = (float*)d_out;

    // ---- workspace layout (reused slots; no growth vs round 1) ----
    char* ws = (char*)d_ws;
    size_t off = 0;
    auto alloc = [&](size_t bytes) -> void* {
        void* p = ws + off; off += (bytes + 255) & ~(size_t)255; return p;
    };
    bf16_t* fqkT  = (bf16_t*)alloc((size_t)2048 * 1024 * 2);  // [n*R+r][d]
    bf16_t* fvT   = (bf16_t*)alloc((size_t)2048 * 1024 * 2);
    bf16_t* fknT  = (bf16_t*)alloc((size_t)1024 * 1024 * 2);  // [n*KR+r][d]
    bf16_t* rqkT  = (bf16_t*)alloc((size_t)1024 * 2048 * 2);  // [d][n*R+r]
    bf16_t* rvT   = (bf16_t*)alloc((size_t)1024 * 2048 * 2);
    bf16_t* rknT  = (bf16_t*)alloc((size_t)1024 * 1024 * 2);  // [d][n*KR+r]
    bf16_t* woB   = (bf16_t*)alloc((size_t)1024 * 1024 * 2);  // W_O as-is = Bt
    bf16_t* buf_nx = (bf16_t*)alloc((size_t)ROWS * 1024 * 2); // nx / Vt / nx2
    bf16_t* buf_y  = (bf16_t*)alloc((size_t)ROWS * 2048 * 2); // yqk / yv / Qb / yk
    bf16_t* buf_s1 = (bf16_t*)alloc((size_t)ROWS * 2048 * 2); // sq / Kb / sk2
    bf16_t* buf_s2 = (bf16_t*)alloc((size_t)ROWS * 2048 * 2); // sk / Vb
    bf16_t* buf_s3 = (bf16_t*)alloc((size_t)ROWS * 2048 * 2); // sv / attn
    (void)ws_size; (void)in_sizes; (void)n_in; (void)out_size;

    const dim3 blk256(256), blkT(32, 8);

    // ---- weight conversion (bf16, transposed to [N][K]) ----
    tcast_kernel<<<dim3(R_DIM / 32, D_DIM / 32, N_NEU), blkT, 0, stream>>>(f_qk, fqkT, D_DIM, R_DIM);
    tcast_kernel<<<dim3(R_DIM / 32, D_DIM / 32, N_NEU), blkT, 0, stream>>>(f_v, fvT, D_DIM, R_DIM);
    tcast_kernel<<<dim3(KR_DIM / 32, D_DIM / 32, N_NEU), blkT, 0, stream>>>(f_know, fknT, D_DIM, KR_DIM);
    tcast_kernel<<<dim3(D_DIM / 32, 2048 / 32, 1), blkT, 0, stream>>>(r_qk, rqkT, 2048, D_DIM);
    tcast_kernel<<<dim3(D_DIM / 32, 2048 / 32, 1), blkT, 0, stream>>>(r_v, rvT, 2048, D_DIM);
    tcast_kernel<<<dim3(D_DIM / 32, 1024 / 32, 1), blkT, 0, stream>>>(r_know, rknT, 1024, D_DIM);
    cast_kernel<<<dim3((1024 * 1024 / 4 + 255) / 256), blk256, 0, stream>>>(W_O, woB, 1024 * 1024 / 4);

    // ---- LN1 ----
    ln_kernel<<<dim3(ROWS), blk256, 0, stream>>>(x, ln1g, ln1b, buf_nx);

    // ---- feature qk: yqk = nx @ fqkT^T ; sq,sk ----
    gemm_kernel<0><<<dim3(2048 / 128, ROWS / 128), blk256, 0, stream>>>(buf_nx, fqkT, buf_y, nullptr, ROWS, 2048, 1024);
    ws_kernel<<<dim3(ROWS), blk256, 0, stream>>>(buf_y, fqk_wQ, rqk_wQ, buf_s1, R_DIM);
    ws_kernel<<<dim3(ROWS), blk256, 0, stream>>>(buf_y, fqk_wK, rqk_wK, buf_s2, R_DIM);

    // ---- feature v: yv = nx @ fvT^T ; sv ----
    gemm_kernel<0><<<dim3(2048 / 128, ROWS / 128), blk256, 0, stream>>>(buf_nx, fvT, buf_y, nullptr, ROWS, 2048, 1024);
    ws_kernel<<<dim3(ROWS), blk256, 0, stream>>>(buf_y, fv_w, rv_w, buf_s3, R_DIM);

    // ---- restores: Q (buf_y), K (buf_s1), V (buf_s2) ----
    gemm_kernel<0><<<dim3(1024 / 128, ROWS / 128), blk256, 0, stream>>>(buf_s1, rqkT, buf_y, nullptr, ROWS, 1024, 2048);
    gemm_kernel<0><<<dim3(1024 / 128, ROWS / 128), blk256, 0, stream>>>(buf_s2, rqkT, buf_s1, nullptr, ROWS, 1024, 2048);
    gemm_kernel<0><<<dim3(1024 / 128, ROWS / 128), blk256, 0, stream>>>(buf_s3, rvT, buf_s2, nullptr, ROWS, 1024, 2048);

    // ---- V -> Vt [B][D][S] (into buf_nx, free until LN2) ----
    tbf_kernel<<<dim3(D_DIM / 32, S_LEN / 32, B_DIM), blkT, 0, stream>>>(buf_s2, buf_nx, S_LEN, D_DIM);

    // ---- attention: attn (into buf_s3) ----
    fa_kernel<<<dim3(S_LEN / 128, B_DIM * H_NUM), blk256, 0, stream>>>(buf_y, buf_s1, buf_nx, buf_s3);

    // ---- x2 = attn @ W_O^T + x  -> d_out (fp32) ----
    gemm_kernel<1><<<dim3(1024 / 128, ROWS / 128), blk256, 0, stream>>>(buf_s3, woB, d_out, x, ROWS, 1024, 1024);

    // ---- LN2, knowledge path ----
    ln_kernel<<<dim3(ROWS), blk256, 0, stream>>>(out_f, ln2g, ln2b, buf_nx);
    gemm_kernel<0><<<dim3(1024 / 128, ROWS / 128), blk256, 0, stream>>>(buf_nx, fknT, buf_y, nullptr, ROWS, 1024, 1024);
    ws_kernel<<<dim3(ROWS / 2), blk256, 0, stream>>>(buf_y, fkn_w, rkn_w, buf_s1, KR_DIM);

    // ---- out = sk2 @ rknT^T + x2 -> d_out (fp32, resid aliases Cout) ----
    gemm_kernel<1><<<dim3(1024 / 128, ROWS / 128), blk256, 0, stream>>>(buf_s1, rknT, d_out, out_f, ROWS, 1024, 1024);
}

// Round 3
// 399.901 us; speedup vs baseline: 1.5099x; 1.2664x over previous
//
#include <hip/hip_runtime.h>
#include <hip/hip_bf16.h>

// ---------------------------------------------------------------------------
// DAWN block on MI355X.  Round 3: occupancy-driven batching.
//  - feature GEMM fused (N=4096, 1024 blocks)
//  - grouped restore GEMM (M=12288, per-m-block B select, 768 blocks)
//  - split-K=2 GEMMs for W_O / know-feature, reduce fused into LN2 / ws2
//  - fa: q-tile 64 (1024 blocks, 4/CU) + T14 issue-early staging, exp2 domain
// ---------------------------------------------------------------------------

typedef __bf16 bf16_t;
typedef __bf16 bf16x8 __attribute__((ext_vector_type(8)));
typedef float f32x4 __attribute__((ext_vector_type(4)));

#define B_DIM 2
#define S_LEN 2048
#define D_DIM 1024
#define H_NUM 16
#define DH 64
#define N_NEU 8
#define R_DIM 256
#define KR_DIM 128
#define ROWS (B_DIM * S_LEN)   // 4096

static __device__ __forceinline__ void gl_lds16(const void* g, void* l)
{
    __builtin_amdgcn_global_load_lds(
        (__attribute__((address_space(1))) void*)(g),
        (__attribute__((address_space(3))) void*)(l), 16, 0, 0);
}

// ---------------------------------------------------------------------------
// Batched transpose-cast: in[z][I][J] f32 -> out[z][J][I] bf16.  block (32,8)
// ---------------------------------------------------------------------------
__global__ __launch_bounds__(256)
void tcast_kernel(const float* __restrict__ in, bf16_t* __restrict__ out, int I, int J)
{
    __shared__ float t[32][33];
    const int bJ = blockIdx.x * 32, bI = blockIdx.y * 32;
    const size_t boff = (size_t)blockIdx.z * I * J;
    const int tx = threadIdx.x, ty = threadIdx.y;
#pragma unroll
    for (int i = 0; i < 4; i++)
        t[ty * 4 + i][tx] = in[boff + (size_t)(bI + ty * 4 + i) * J + bJ + tx];
    __syncthreads();
#pragma unroll
    for (int i = 0; i < 4; i++)
        out[boff + (size_t)(bJ + ty * 4 + i) * I + bI + tx] = (bf16_t)t[tx][ty * 4 + i];
}

// bf16 transpose: in[z][I][J] -> out[z][J][I].  block (32,8)
__global__ __launch_bounds__(256)
void tbf_kernel(const bf16_t* __restrict__ in, bf16_t* __restrict__ out, int I, int J)
{
    __shared__ bf16_t t[32][33];
    const int bJ = blockIdx.x * 32, bI = blockIdx.y * 32;
    const size_t boff = (size_t)blockIdx.z * I * J;
    const int tx = threadIdx.x, ty = threadIdx.y;
#pragma unroll
    for (int i = 0; i < 4; i++)
        t[ty * 4 + i][tx] = in[boff + (size_t)(bI + ty * 4 + i) * J + bJ + tx];
    __syncthreads();
#pragma unroll
    for (int i = 0; i < 4; i++)
        out[boff + (size_t)(bJ + ty * 4 + i) * I + bI + tx] = t[tx][ty * 4 + i];
}

// plain cast fp32 -> bf16 (vectorized by 4)
__global__ __launch_bounds__(256)
void cast_kernel(const float* __restrict__ in, bf16_t* __restrict__ out, int n4)
{
    int i = blockIdx.x * 256 + threadIdx.x;
    if (i < n4) {
        float4 v = ((const float4*)in)[i];
        bf16_t* op = out + (size_t)i * 4;
        op[0] = (bf16_t)v.x; op[1] = (bf16_t)v.y; op[2] = (bf16_t)v.z; op[3] = (bf16_t)v.w;
    }
}

// ---------------------------------------------------------------------------
// LayerNorm over D=1024, one row per block. fp32 in, bf16 out.
// ---------------------------------------------------------------------------
__global__ __launch_bounds__(256)
void ln_kernel(const float* __restrict__ x, const float* __restrict__ g,
               const float* __restrict__ beta, bf16_t* __restrict__ out)
{
    __shared__ float red[4];
    const int row = blockIdx.x;
    const int tid = threadIdx.x;
    float4 v = *(const float4*)&x[(size_t)row * D_DIM + tid * 4];

    float s = v.x + v.y + v.z + v.w;
#pragma unroll
    for (int o = 32; o; o >>= 1) s += __shfl_down(s, o);
    if ((tid & 63) == 0) red[tid >> 6] = s;
    __syncthreads();
    float mean = (red[0] + red[1] + red[2] + red[3]) * (1.f / D_DIM);
    __syncthreads();

    float dx = v.x - mean, dy = v.y - mean, dz = v.z - mean, dw = v.w - mean;
    float q = dx * dx + dy * dy + dz * dz + dw * dw;
#pragma unroll
    for (int o = 32; o; o >>= 1) q += __shfl_down(q, o);
    if ((tid & 63) == 0) red[tid >> 6] = q;
    __syncthreads();
    float var = (red[0] + red[1] + red[2] + red[3]) * (1.f / D_DIM);
    float rstd = rsqrtf(var + 1e-5f);

    float4 gv = *(const float4*)&g[tid * 4];
    float4 bv = *(const float4*)&beta[tid * 4];
    bf16_t* op = out + (size_t)row * D_DIM + tid * 4;
    op[0] = (bf16_t)(dx * rstd * gv.x + bv.x);
    op[1] = (bf16_t)(dy * rstd * gv.y + bv.y);
    op[2] = (bf16_t)(dz * rstd * gv.z + bv.z);
    op[3] = (bf16_t)(dw * rstd * gv.w + bv.w);
}

// ---------------------------------------------------------------------------
// LN2 with fused split-K reduce + residual:  sum = x + P0 + P1 (fp32, written
// to outf), then LN(sum) -> bf16 outn.
// ---------------------------------------------------------------------------
__global__ __launch_bounds__(256)
void ln2x_kernel(const float* __restrict__ x, const float* __restrict__ P0,
                 const float* __restrict__ P1, const float* __restrict__ g,
                 const float* __restrict__ beta, float* __restrict__ outf,
                 bf16_t* __restrict__ outn)
{
    __shared__ float red[4];
    const int row = blockIdx.x;
    const int tid = threadIdx.x;
    const size_t base = (size_t)row * D_DIM + tid * 4;
    float4 v  = *(const float4*)&x[base];
    float4 p0 = *(const float4*)&P0[base];
    float4 p1 = *(const float4*)&P1[base];
    v.x += p0.x + p1.x; v.y += p0.y + p1.y; v.z += p0.z + p1.z; v.w += p0.w + p1.w;
    *(float4*)&outf[base] = v;

    float s = v.x + v.y + v.z + v.w;
#pragma unroll
    for (int o = 32; o; o >>= 1) s += __shfl_down(s, o);
    if ((tid & 63) == 0) red[tid >> 6] = s;
    __syncthreads();
    float mean = (red[0] + red[1] + red[2] + red[3]) * (1.f / D_DIM);
    __syncthreads();

    float dx = v.x - mean, dy = v.y - mean, dz = v.z - mean, dw = v.w - mean;
    float q = dx * dx + dy * dy + dz * dz + dw * dw;
#pragma unroll
    for (int o = 32; o; o >>= 1) q += __shfl_down(q, o);
    if ((tid & 63) == 0) red[tid >> 6] = q;
    __syncthreads();
    float var = (red[0] + red[1] + red[2] + red[3]) * (1.f / D_DIM);
    float rstd = rsqrtf(var + 1e-5f);

    float4 gv = *(const float4*)&g[tid * 4];
    float4 bv = *(const float4*)&beta[tid * 4];
    bf16_t* op = outn + base;
    op[0] = (bf16_t)(dx * rstd * gv.x + bv.x);
    op[1] = (bf16_t)(dy * rstd * gv.y + bv.y);
    op[2] = (bf16_t)(dz * rstd * gv.z + bv.z);
    op[3] = (bf16_t)(dw * rstd * gv.w + bv.w);
}

// ---------------------------------------------------------------------------
// Weighted-sum: h[r] = sum_n wf[n]*y[n*R+r]; s[n*R+r] = wr[n]*h[r].
// y has row stride ldy (fused feature buffer).
// ---------------------------------------------------------------------------
__global__ __launch_bounds__(256)
void ws_kernel(const bf16_t* __restrict__ y, int ldy, const float* __restrict__ wf,
               const float* __restrict__ wr, bf16_t* __restrict__ sout)
{
    const int r = threadIdx.x;     // 0..255
    const int row = blockIdx.x;
    const bf16_t* yrow = y + (size_t)row * ldy;
    const float* wfp = wf + row * N_NEU;
    const float* wrp = wr + row * N_NEU;
    float acc = 0.f;
#pragma unroll
    for (int n = 0; n < N_NEU; n++) acc += wfp[n] * (float)yrow[n * R_DIM + r];
    bf16_t* srow = sout + (size_t)row * N_NEU * R_DIM;
#pragma unroll
    for (int n = 0; n < N_NEU; n++) srow[n * R_DIM + r] = (bf16_t)(wrp[n] * acc);
}

// know-path ws with fused split-K reduce: y = P0+P1 (fp32 partials), KR=128.
__global__ __launch_bounds__(256)
void ws2_kernel(const float* __restrict__ P0, const float* __restrict__ P1,
                const float* __restrict__ wf, const float* __restrict__ wr,
                bf16_t* __restrict__ sout)
{
    const int lr = threadIdx.x >> 7;       // 0..1
    const int r  = threadIdx.x & 127;
    const int row = blockIdx.x * 2 + lr;
    const size_t rb = (size_t)row * (N_NEU * KR_DIM);
    const float* wfp = wf + row * N_NEU;
    const float* wrp = wr + row * N_NEU;
    float acc = 0.f;
#pragma unroll
    for (int n = 0; n < N_NEU; n++) {
        size_t i = rb + n * KR_DIM + r;
        acc += wfp[n] * (P0[i] + P1[i]);
    }
    bf16_t* srow = sout + rb;
#pragma unroll
    for (int n = 0; n < N_NEU; n++) srow[n * KR_DIM + r] = (bf16_t)(wrp[n] * acc);
}

// ---------------------------------------------------------------------------
// GEMM (m97 structure): C[M,N] = A[M,K] @ Bsel[N,K]^T.  128x128 tile, BK=32,
// global_load_lds width=16 into linear LDS, 2 barriers/K-step.
// B select: blockIdx.y < splitMy ? Bt : Bt2 (grouped GEMM).
// EPI=0: bf16 C.  EPI=1: fp32 C = acc + resid.  EPI=2: fp32 partial per
// blockIdx.z (split-K=2), written to Cout + z*M*N.
// ---------------------------------------------------------------------------
template<int EPI>
__global__ __launch_bounds__(256)
void gemm_kernel(const bf16_t* __restrict__ A, const bf16_t* __restrict__ Bt,
                 const bf16_t* __restrict__ Bt2, int splitMy,
                 void* Cout, const float* resid, int M, int N, int K)
{
    __shared__ bf16_t As[128][32];
    __shared__ bf16_t Bs[128][32];
    const int tid = threadIdx.x;
    const int l = tid & 63, w = tid >> 6;
    const int wr = w >> 1, wc = w & 1;
    const int m0 = blockIdx.y * 128, n0 = blockIdx.x * 128;
    const bf16_t* Bsel = ((int)blockIdx.y < splitMy) ? Bt : Bt2;

    int kbeg = 0, kend = K;
    if constexpr (EPI == 2) { const int half = K >> 1; kbeg = blockIdx.z * half; kend = kbeg + half; }

    const int srow = l >> 2;
    const int scol = (l & 3) * 8;
    const bf16_t* Ag0 = A    + (size_t)(m0 + w * 32 + srow) * K + scol;
    const bf16_t* Ag1 = Ag0 + (size_t)16 * K;
    const bf16_t* Bg0 = Bsel + (size_t)(n0 + w * 32 + srow) * K + scol;
    const bf16_t* Bg1 = Bg0 + (size_t)16 * K;
    char* Asb = (char*)&As[0][0] + w * 2048;
    char* Bsb = (char*)&Bs[0][0] + w * 2048;

    f32x4 acc[4][4];
    const f32x4 zero = {0.f, 0.f, 0.f, 0.f};
#pragma unroll
    for (int i = 0; i < 4; i++)
#pragma unroll
        for (int j = 0; j < 4; j++) acc[i][j] = zero;

    const int fr = l & 15;
    const int fk = (l >> 4) * 8;

    for (int k0 = kbeg; k0 < kend; k0 += 32) {
        gl_lds16(Ag0 + k0, Asb);
        gl_lds16(Ag1 + k0, Asb + 1024);
        gl_lds16(Bg0 + k0, Bsb);
        gl_lds16(Bg1 + k0, Bsb + 1024);
        __syncthreads();

        bf16x8 af[4], bv[4];
#pragma unroll
        for (int i = 0; i < 4; i++) af[i] = *(const bf16x8*)&As[wr * 64 + i * 16 + fr][fk];
#pragma unroll
        for (int i = 0; i < 4; i++) bv[i] = *(const bf16x8*)&Bs[wc * 64 + i * 16 + fr][fk];
#pragma unroll
        for (int mi = 0; mi < 4; mi++)
#pragma unroll
            for (int ni = 0; ni < 4; ni++)
                acc[mi][ni] = __builtin_amdgcn_mfma_f32_16x16x32_bf16(af[mi], bv[ni], acc[mi][ni], 0, 0, 0);
        __syncthreads();
    }

    const int orow = (l >> 4) * 4;
    const int ocol = l & 15;
#pragma unroll
    for (int mi = 0; mi < 4; mi++)
#pragma unroll
        for (int ni = 0; ni < 4; ni++)
#pragma unroll
            for (int j = 0; j < 4; j++) {
                int row = m0 + wr * 64 + mi * 16 + orow + j;
                int col = n0 + wc * 64 + ni * 16 + ocol;
                size_t idx = (size_t)row * N + col;
                if constexpr (EPI == 0) {
                    ((bf16_t*)Cout)[idx] = (bf16_t)acc[mi][ni][j];
                } else if constexpr (EPI == 1) {
                    ((float*)Cout)[idx] = acc[mi][ni][j] + resid[idx];
                } else {
                    ((float*)Cout)[(size_t)blockIdx.z * M * N + idx] = acc[mi][ni][j];
                }
            }
}

// ---------------------------------------------------------------------------
// Causal flash attention.  Q/K/O: [B*S][1024] bf16 (head h = cols h*64..+64).
// Vt: [B][1024][2048] bf16 (pre-transposed V).
// Grid (S/64, B*H); 256 thr = 4 waves; wave w owns q rows q0+w*16..+16.
// KVBLK=64, T14 issue-early staging, exp2 softmax domain.
// ---------------------------------------------------------------------------
__global__ __launch_bounds__(256)
void fa_kernel(const bf16_t* __restrict__ Q, const bf16_t* __restrict__ K,
               const bf16_t* __restrict__ Vt, bf16_t* __restrict__ O)
{
    __shared__ bf16_t Ks[64][72];
    __shared__ bf16_t Vs[64][72];
    __shared__ bf16_t Ps[4][16][72];

    const int tid = threadIdx.x;
    const int l = tid & 63, w = tid >> 6;
    const int bh = blockIdx.y;
    const int b = bh >> 4, h = bh & 15;
    const int q0 = ((int)gridDim.x - 1 - (int)blockIdx.x) * 64;  // heavy blocks first

    const bf16_t* Qp = Q + (size_t)b * S_LEN * D_DIM + h * DH;
    const bf16_t* Kp = K + (size_t)b * S_LEN * D_DIM + h * DH;
    const bf16_t* Vp = Vt + (size_t)b * D_DIM * S_LEN + (size_t)h * DH * S_LEN;

    const int fr = l & 15, fg = l >> 4, fk = fg * 8;

    bf16x8 qf[2];
#pragma unroll
    for (int ks = 0; ks < 2; ks++)
        qf[ks] = *(const bf16x8*)(Qp + (size_t)(q0 + w * 16 + fr) * D_DIM + ks * 32 + fk);

    const f32x4 zero = {0.f, 0.f, 0.f, 0.f};
    f32x4 o[4];
    float m_r[4], l_r[4];
#pragma unroll
    for (int j = 0; j < 4; j++) { o[j] = zero; m_r[j] = -1e30f; l_r[j] = 0.f; }

    const int srow = tid >> 2;
    const int scol = (tid & 3) * 16;
    const bf16_t* Kst = Kp + (size_t)srow * D_DIM + scol;
    const bf16_t* Vst = Vp + (size_t)srow * S_LEN + scol;

    const int nt = q0 / 64 + 1;
    const float C_LOG2 = 0.125f * 1.44269504f;   // 1/sqrt(DH) * log2(e)

    // prologue: issue loads for tile 0
    uint4 kva = *(const uint4*)(Kst);
    uint4 kvb = *(const uint4*)(Kst + 8);
    uint4 vva = *(const uint4*)(Vst);
    uint4 vvb = *(const uint4*)(Vst + 8);

    for (int t = 0; t < nt; t++) {
        const int k0 = t * 64;
        __syncthreads();              // previous tile's reads complete
        *(uint4*)&Ks[srow][scol]     = kva;
        *(uint4*)&Ks[srow][scol + 8] = kvb;
        *(uint4*)&Vs[srow][scol]     = vva;
        *(uint4*)&Vs[srow][scol + 8] = vvb;
        __syncthreads();

        if (t + 1 < nt) {             // T14: issue next tile's loads now
            const int kn = k0 + 64;
            kva = *(const uint4*)(Kst + (size_t)kn * D_DIM);
            kvb = *(const uint4*)(Kst + (size_t)kn * D_DIM + 8);
            vva = *(const uint4*)(Vst + kn);
            vvb = *(const uint4*)(Vst + kn + 8);
        }

        // ---- QK^T: 16 q-rows x 64 keys ----
        f32x4 sc[4];
#pragma unroll
        for (int ni = 0; ni < 4; ni++) sc[ni] = zero;
#pragma unroll
        for (int ks = 0; ks < 2; ks++) {
#pragma unroll
            for (int ni = 0; ni < 4; ni++) {
                bf16x8 kf = *(const bf16x8*)&Ks[ni * 16 + fr][ks * 32 + fk];
                sc[ni] = __builtin_amdgcn_mfma_f32_16x16x32_bf16(qf[ks], kf, sc[ni], 0, 0, 0);
            }
        }

        // ---- scale to log2 domain + causal mask ----
        float p[4][4];
#pragma unroll
        for (int ni = 0; ni < 4; ni++) {
            const int key = k0 + ni * 16 + fr;
#pragma unroll
            for (int j = 0; j < 4; j++) {
                const int qg = q0 + w * 16 + fg * 4 + j;
                p[ni][j] = (key <= qg) ? sc[ni][j] * C_LOG2 : -1e30f;
            }
        }

        // ---- online softmax (exp2 domain), rows j ----
#pragma unroll
        for (int j = 0; j < 4; j++) {
            float rmax = fmaxf(fmaxf(p[0][j], p[1][j]), fmaxf(p[2][j], p[3][j]));
#pragma unroll
            for (int d = 1; d < 16; d <<= 1) rmax = fmaxf(rmax, __shfl_xor(rmax, d));
            float mnew = fmaxf(m_r[j], rmax);
            float scale = exp2f(m_r[j] - mnew);
            float rsum = 0.f;
#pragma unroll
            for (int ni = 0; ni < 4; ni++) {
                float e = exp2f(p[ni][j] - mnew);
                p[ni][j] = e; rsum += e;
            }
#pragma unroll
            for (int d = 1; d < 16; d <<= 1) rsum += __shfl_xor(rsum, d);
            l_r[j] = l_r[j] * scale + rsum;
            m_r[j] = mnew;
#pragma unroll
            for (int nc = 0; nc < 4; nc++) o[nc][j] *= scale;
        }

        // ---- P -> A-layout via per-wave LDS bounce ----
#pragma unroll
        for (int ni = 0; ni < 4; ni++)
#pragma unroll
            for (int j = 0; j < 4; j++)
                Ps[w][fg * 4 + j][ni * 16 + fr] = (bf16_t)p[ni][j];

        // ---- PV ----
#pragma unroll
        for (int ks = 0; ks < 2; ks++) {
            bf16x8 pa = *(const bf16x8*)&Ps[w][fr][ks * 32 + fk];
#pragma unroll
            for (int nc = 0; nc < 4; nc++) {
                bf16x8 vf = *(const bf16x8*)&Vs[nc * 16 + fr][ks * 32 + fk];
                o[nc] = __builtin_amdgcn_mfma_f32_16x16x32_bf16(pa, vf, o[nc], 0, 0, 0);
            }
        }
    }

    // ---- epilogue ----
#pragma unroll
    for (int j = 0; j < 4; j++) {
        const float inv = 1.f / l_r[j];
        const int q = q0 + w * 16 + fg * 4 + j;
        bf16_t* op = O + (size_t)(b * S_LEN + q) * D_DIM + h * DH;
#pragma unroll
        for (int nc = 0; nc < 4; nc++)
            op[nc * 16 + fr] = (bf16_t)(o[nc][j] * inv);
    }
}

// ---------------------------------------------------------------------------
extern "C" void kernel_launch(void* const* d_in, const int* in_sizes, int n_in,
                              void* d_out, int out_size, void* d_ws, size_t ws_size,
                              hipStream_t stream)
{
    const float* x      = (const float*)d_in[0];
    const float* fqk_wQ = (const float*)d_in[1];
    const float* fqk_wK = (const float*)d_in[2];
    const float* fv_w   = (const float*)d_in[3];
    const float* rqk_wQ = (const float*)d_in[4];
    const float* rqk_wK = (const float*)d_in[5];
    const float* rv_w   = (const float*)d_in[6];
    const float* fkn_w  = (const float*)d_in[7];
    const float* rkn_w  = (const float*)d_in[8];
    const float* f_qk   = (const float*)d_in[9];
    const float* f_v    = (const float*)d_in[10];
    const float* r_qk   = (const float*)d_in[11];
    const float* r_v    = (const float*)d_in[12];
    const float* f_know = (const float*)d_in[13];
    const float* r_know = (const float*)d_in[14];
    const float* W_O    = (const float*)d_in[15];
    const float* ln1g   = (const float*)d_in[16];
    const float* ln1b   = (const float*)d_in[17];
    const float* ln2g   = (const float*)d_in[18];
    const float* ln2b   = (const float*)d_in[19];
    float* out_f = (float*)d_out;
    (void)ws_size; (void)in_sizes; (void)n_in; (void)out_size;

    // ---- workspace layout (102 MB peak, heavy aliasing — see comments) ----
    char* ws = (char*)d_ws;
    const size_t MB = 1024 * 1024;
    bf16_t* rqkT   = (bf16_t*)(ws + 0 * MB);    // [1024][2048]  4MB  persistent
    bf16_t* rvT    = (bf16_t*)(ws + 4 * MB);    // [1024][2048]  4MB
    bf16_t* rknT   = (bf16_t*)(ws + 8 * MB);    // [1024][1024]  2MB
    bf16_t* woB    = (bf16_t*)(ws + 10 * MB);   // [1024][1024]  2MB
    bf16_t* fknT   = (bf16_t*)(ws + 12 * MB);   // [1024][1024]  2MB
    bf16_t* buf_nx = (bf16_t*)(ws + 14 * MB);   // 8MB: nx -> Vt -> nx2
    bf16_t* buf_y  = (bf16_t*)(ws + 22 * MB);   // 32MB: y[4096][4096] -> QKV[12288][1024]
    char*   buf_s  = ws + 54 * MB;              // 48MB: fqkT/fvT -> sq|sk|sv -> attn/partials/sk2
    bf16_t* fqkT   = (bf16_t*)(buf_s);               // [2048][1024] 4MB (pre-ws only)
    bf16_t* fvT    = (bf16_t*)(buf_s + 4 * MB);      // contiguous with fqkT -> N=4096 B
    bf16_t* s_q    = (bf16_t*)(buf_s);               // rows 0..4095     of [12288][2048]
    bf16_t* s_k    = (bf16_t*)(buf_s) + (size_t)4096 * 2048;
    bf16_t* s_v    = (bf16_t*)(buf_s) + (size_t)8192 * 2048;
    bf16_t* attn   = (bf16_t*)(buf_s);               // [4096][1024] 8MB (after restores)
    float*  P0     = (float*)(buf_s + 16 * MB);      // W_O split-K partials, 2x16MB
    float*  P0k    = (float*)(buf_s);                // know split-K partials
    float*  P1k    = (float*)(buf_s + 16 * MB);
    bf16_t* sk2    = (bf16_t*)(buf_s + 32 * MB);     // [4096][1024] 8MB
    bf16_t* Qb     = buf_y;                          // QKV contiguous [12288][1024]
    bf16_t* Kb     = buf_y + (size_t)4096 * 1024;
    bf16_t* Vb     = buf_y + (size_t)8192 * 1024;
    bf16_t* Vt     = buf_nx;                         // [2][1024][2048]

    const dim3 blk256(256), blkT(32, 8);

    // ---- weight conversion ----
    tcast_kernel<<<dim3(R_DIM / 32, D_DIM / 32, N_NEU), blkT, 0, stream>>>(f_qk, fqkT, D_DIM, R_DIM);
    tcast_kernel<<<dim3(R_DIM / 32, D_DIM / 32, N_NEU), blkT, 0, stream>>>(f_v, fvT, D_DIM, R_DIM);
    tcast_kernel<<<dim3(KR_DIM / 32, D_DIM / 32, N_NEU), blkT, 0, stream>>>(f_know, fknT, D_DIM, KR_DIM);
    tcast_kernel<<<dim3(D_DIM / 32, 2048 / 32, 1), blkT, 0, stream>>>(r_qk, rqkT, 2048, D_DIM);
    tcast_kernel<<<dim3(D_DIM / 32, 2048 / 32, 1), blkT, 0, stream>>>(r_v, rvT, 2048, D_DIM);
    tcast_kernel<<<dim3(D_DIM / 32, 1024 / 32, 1), blkT, 0, stream>>>(r_know, rknT, 1024, D_DIM);
    cast_kernel<<<dim3(1024 * 1024 / 4 / 256), blk256, 0, stream>>>(W_O, woB, 1024 * 1024 / 4);

    // ---- LN1 ----
    ln_kernel<<<dim3(ROWS), blk256, 0, stream>>>(x, ln1g, ln1b, buf_nx);

    // ---- fused feature GEMM: y[4096][4096] = nx @ [fqkT;fvT]^T  (1024 blocks) ----
    gemm_kernel<0><<<dim3(32, 32), blk256, 0, stream>>>(buf_nx, fqkT, fqkT, 1 << 30, buf_y, nullptr, 4096, 4096, 1024);

    // ---- weighted sums -> sq|sk|sv [12288][2048] ----
    ws_kernel<<<dim3(ROWS), blk256, 0, stream>>>(buf_y,        4096, fqk_wQ, rqk_wQ, s_q);
    ws_kernel<<<dim3(ROWS), blk256, 0, stream>>>(buf_y,        4096, fqk_wK, rqk_wK, s_k);
    ws_kernel<<<dim3(ROWS), blk256, 0, stream>>>(buf_y + 2048, 4096, fv_w,   rv_w,   s_v);

    // ---- grouped restore GEMM: QKV[12288][1024]  (768 blocks, B-select) ----
    gemm_kernel<0><<<dim3(8, 96), blk256, 0, stream>>>((bf16_t*)buf_s, rqkT, rvT, 64, buf_y, nullptr, 12288, 1024, 2048);

    // ---- V -> Vt ----
    tbf_kernel<<<dim3(D_DIM / 32, S_LEN / 32, B_DIM), blkT, 0, stream>>>(Vb, Vt, S_LEN, D_DIM);

    // ---- attention (1024 blocks) ----
    fa_kernel<<<dim3(S_LEN / 64, B_DIM * H_NUM), blk256, 0, stream>>>(Qb, Kb, Vt, attn);

    // ---- W_O split-K=2: partials P0/P1 (512 blocks) ----
    gemm_kernel<2><<<dim3(8, 32, 2), blk256, 0, stream>>>(attn, woB, woB, 1 << 30, P0, nullptr, 4096, 1024, 1024);

    // ---- LN2 fused: d_out = x + P0 + P1; nx2 = LN(d_out) ----
    ln2x_kernel<<<dim3(ROWS), blk256, 0, stream>>>(x, P0, P0 + (size_t)4096 * 1024, ln2g, ln2b, out_f, buf_nx);

    // ---- know feature split-K=2: partials P0k/P1k (512 blocks) ----
    gemm_kernel<2><<<dim3(8, 32, 2), blk256, 0, stream>>>(buf_nx, fknT, fknT, 1 << 30, P0k, nullptr, 4096, 1024, 1024);

    // ---- know ws (fused reduce) -> sk2 ----
    ws2_kernel<<<dim3(ROWS / 2), blk256, 0, stream>>>(P0k, P1k, fkn_w, rkn_w, sk2);

    // ---- out = sk2 @ rknT^T + x2 -> d_out ----
    gemm_kernel<1><<<dim3(8, 32), blk256, 0, stream>>>(sk2, rknT, rknT, 1 << 30, d_out, out_f, 4096, 1024, 1024);
}

// Round 4
// 389.366 us; speedup vs baseline: 1.5508x; 1.0271x over previous
//
#include <hip/hip_runtime.h>
#include <hip/hip_bf16.h>

// ---------------------------------------------------------------------------
// DAWN block on MI355X.  Round 4: fa locality + balance.
//  - fa: XCD-chunked head mapping (K/V L2-resident per XCD), zigzag q pairing,
//        defer-max (T13), setprio (T5)
//  - GEMM: XCD-chunked block swizzle for A-panel L2 reuse
//  - ws x3 fused into one kernel
// ---------------------------------------------------------------------------

typedef __bf16 bf16_t;
typedef __bf16 bf16x8 __attribute__((ext_vector_type(8)));
typedef float f32x4 __attribute__((ext_vector_type(4)));

#define B_DIM 2
#define S_LEN 2048
#define D_DIM 1024
#define H_NUM 16
#define DH 64
#define N_NEU 8
#define R_DIM 256
#define KR_DIM 128
#define ROWS (B_DIM * S_LEN)   // 4096

static __device__ __forceinline__ void gl_lds16(const void* g, void* l)
{
    __builtin_amdgcn_global_load_lds(
        (__attribute__((address_space(1))) void*)(g),
        (__attribute__((address_space(3))) void*)(l), 16, 0, 0);
}

// ---------------------------------------------------------------------------
// Batched transpose-cast: in[z][I][J] f32 -> out[z][J][I] bf16.  block (32,8)
// ---------------------------------------------------------------------------
__global__ __launch_bounds__(256)
void tcast_kernel(const float* __restrict__ in, bf16_t* __restrict__ out, int I, int J)
{
    __shared__ float t[32][33];
    const int bJ = blockIdx.x * 32, bI = blockIdx.y * 32;
    const size_t boff = (size_t)blockIdx.z * I * J;
    const int tx = threadIdx.x, ty = threadIdx.y;
#pragma unroll
    for (int i = 0; i < 4; i++)
        t[ty * 4 + i][tx] = in[boff + (size_t)(bI + ty * 4 + i) * J + bJ + tx];
    __syncthreads();
#pragma unroll
    for (int i = 0; i < 4; i++)
        out[boff + (size_t)(bJ + ty * 4 + i) * I + bI + tx] = (bf16_t)t[tx][ty * 4 + i];
}

// bf16 transpose: in[z][I][J] -> out[z][J][I].  block (32,8)
__global__ __launch_bounds__(256)
void tbf_kernel(const bf16_t* __restrict__ in, bf16_t* __restrict__ out, int I, int J)
{
    __shared__ bf16_t t[32][33];
    const int bJ = blockIdx.x * 32, bI = blockIdx.y * 32;
    const size_t boff = (size_t)blockIdx.z * I * J;
    const int tx = threadIdx.x, ty = threadIdx.y;
#pragma unroll
    for (int i = 0; i < 4; i++)
        t[ty * 4 + i][tx] = in[boff + (size_t)(bI + ty * 4 + i) * J + bJ + tx];
    __syncthreads();
#pragma unroll
    for (int i = 0; i < 4; i++)
        out[boff + (size_t)(bJ + ty * 4 + i) * I + bI + tx] = t[tx][ty * 4 + i];
}

// plain cast fp32 -> bf16 (vectorized by 4)
__global__ __launch_bounds__(256)
void cast_kernel(const float* __restrict__ in, bf16_t* __restrict__ out, int n4)
{
    int i = blockIdx.x * 256 + threadIdx.x;
    if (i < n4) {
        float4 v = ((const float4*)in)[i];
        bf16_t* op = out + (size_t)i * 4;
        op[0] = (bf16_t)v.x; op[1] = (bf16_t)v.y; op[2] = (bf16_t)v.z; op[3] = (bf16_t)v.w;
    }
}

// ---------------------------------------------------------------------------
// LayerNorm over D=1024, one row per block. fp32 in, bf16 out.
// ---------------------------------------------------------------------------
__global__ __launch_bounds__(256)
void ln_kernel(const float* __restrict__ x, const float* __restrict__ g,
               const float* __restrict__ beta, bf16_t* __restrict__ out)
{
    __shared__ float red[4];
    const int row = blockIdx.x;
    const int tid = threadIdx.x;
    float4 v = *(const float4*)&x[(size_t)row * D_DIM + tid * 4];

    float s = v.x + v.y + v.z + v.w;
#pragma unroll
    for (int o = 32; o; o >>= 1) s += __shfl_down(s, o);
    if ((tid & 63) == 0) red[tid >> 6] = s;
    __syncthreads();
    float mean = (red[0] + red[1] + red[2] + red[3]) * (1.f / D_DIM);
    __syncthreads();

    float dx = v.x - mean, dy = v.y - mean, dz = v.z - mean, dw = v.w - mean;
    float q = dx * dx + dy * dy + dz * dz + dw * dw;
#pragma unroll
    for (int o = 32; o; o >>= 1) q += __shfl_down(q, o);
    if ((tid & 63) == 0) red[tid >> 6] = q;
    __syncthreads();
    float var = (red[0] + red[1] + red[2] + red[3]) * (1.f / D_DIM);
    float rstd = rsqrtf(var + 1e-5f);

    float4 gv = *(const float4*)&g[tid * 4];
    float4 bv = *(const float4*)&beta[tid * 4];
    bf16_t* op = out + (size_t)row * D_DIM + tid * 4;
    op[0] = (bf16_t)(dx * rstd * gv.x + bv.x);
    op[1] = (bf16_t)(dy * rstd * gv.y + bv.y);
    op[2] = (bf16_t)(dz * rstd * gv.z + bv.z);
    op[3] = (bf16_t)(dw * rstd * gv.w + bv.w);
}

// ---------------------------------------------------------------------------
// LN2 with fused split-K reduce + residual:  sum = x + P0 + P1 -> outf (fp32),
// then LN(sum) -> bf16 outn.
// ---------------------------------------------------------------------------
__global__ __launch_bounds__(256)
void ln2x_kernel(const float* __restrict__ x, const float* __restrict__ P0,
                 const float* __restrict__ P1, const float* __restrict__ g,
                 const float* __restrict__ beta, float* __restrict__ outf,
                 bf16_t* __restrict__ outn)
{
    __shared__ float red[4];
    const int row = blockIdx.x;
    const int tid = threadIdx.x;
    const size_t base = (size_t)row * D_DIM + tid * 4;
    float4 v  = *(const float4*)&x[base];
    float4 p0 = *(const float4*)&P0[base];
    float4 p1 = *(const float4*)&P1[base];
    v.x += p0.x + p1.x; v.y += p0.y + p1.y; v.z += p0.z + p1.z; v.w += p0.w + p1.w;
    *(float4*)&outf[base] = v;

    float s = v.x + v.y + v.z + v.w;
#pragma unroll
    for (int o = 32; o; o >>= 1) s += __shfl_down(s, o);
    if ((tid & 63) == 0) red[tid >> 6] = s;
    __syncthreads();
    float mean = (red[0] + red[1] + red[2] + red[3]) * (1.f / D_DIM);
    __syncthreads();

    float dx = v.x - mean, dy = v.y - mean, dz = v.z - mean, dw = v.w - mean;
    float q = dx * dx + dy * dy + dz * dz + dw * dw;
#pragma unroll
    for (int o = 32; o; o >>= 1) q += __shfl_down(q, o);
    if ((tid & 63) == 0) red[tid >> 6] = q;
    __syncthreads();
    float var = (red[0] + red[1] + red[2] + red[3]) * (1.f / D_DIM);
    float rstd = rsqrtf(var + 1e-5f);

    float4 gv = *(const float4*)&g[tid * 4];
    float4 bv = *(const float4*)&beta[tid * 4];
    bf16_t* op = outn + base;
    op[0] = (bf16_t)(dx * rstd * gv.x + bv.x);
    op[1] = (bf16_t)(dy * rstd * gv.y + bv.y);
    op[2] = (bf16_t)(dz * rstd * gv.z + bv.z);
    op[3] = (bf16_t)(dw * rstd * gv.w + bv.w);
}

// ---------------------------------------------------------------------------
// Fused weighted-sum for Q/K/V: reads y row once, writes sq, sk, sv.
// y: [4096][4096] (cols 0..2047 = qk-neurons, 2048..4095 = v-neurons).
// ---------------------------------------------------------------------------
__global__ __launch_bounds__(256)
void wsf_kernel(const bf16_t* __restrict__ y,
                const float* __restrict__ wfQ, const float* __restrict__ wrQ,
                const float* __restrict__ wfK, const float* __restrict__ wrK,
                const float* __restrict__ wfV, const float* __restrict__ wrV,
                bf16_t* __restrict__ sq, bf16_t* __restrict__ sk, bf16_t* __restrict__ sv)
{
    const int r = threadIdx.x;     // 0..255
    const int row = blockIdx.x;
    const bf16_t* yrow = y + (size_t)row * 4096;
    const float* fQ = wfQ + row * N_NEU;
    const float* fK = wfK + row * N_NEU;
    const float* fV = wfV + row * N_NEU;
    float aQ = 0.f, aK = 0.f, aV = 0.f;
#pragma unroll
    for (int n = 0; n < N_NEU; n++) {
        float yq = (float)yrow[n * R_DIM + r];
        float yv = (float)yrow[2048 + n * R_DIM + r];
        aQ += fQ[n] * yq;
        aK += fK[n] * yq;
        aV += fV[n] * yv;
    }
    const float* rQ = wrQ + row * N_NEU;
    const float* rK = wrK + row * N_NEU;
    const float* rV = wrV + row * N_NEU;
    const size_t rb = (size_t)row * 2048;
#pragma unroll
    for (int n = 0; n < N_NEU; n++) {
        sq[rb + n * R_DIM + r] = (bf16_t)(rQ[n] * aQ);
        sk[rb + n * R_DIM + r] = (bf16_t)(rK[n] * aK);
        sv[rb + n * R_DIM + r] = (bf16_t)(rV[n] * aV);
    }
}

// know-path ws with fused split-K reduce: y = P0+P1 (fp32 partials), KR=128.
__global__ __launch_bounds__(256)
void ws2_kernel(const float* __restrict__ P0, const float* __restrict__ P1,
                const float* __restrict__ wf, const float* __restrict__ wr,
                bf16_t* __restrict__ sout)
{
    const int lr = threadIdx.x >> 7;
    const int r  = threadIdx.x & 127;
    const int row = blockIdx.x * 2 + lr;
    const size_t rb = (size_t)row * (N_NEU * KR_DIM);
    const float* wfp = wf + row * N_NEU;
    const float* wrp = wr + row * N_NEU;
    float acc = 0.f;
#pragma unroll
    for (int n = 0; n < N_NEU; n++) {
        size_t i = rb + n * KR_DIM + r;
        acc += wfp[n] * (P0[i] + P1[i]);
    }
    bf16_t* srow = sout + rb;
#pragma unroll
    for (int n = 0; n < N_NEU; n++) srow[n * KR_DIM + r] = (bf16_t)(wrp[n] * acc);
}

// ---------------------------------------------------------------------------
// GEMM (m97 structure): C[M,N] = A[M,K] @ Bsel[N,K]^T.  128x128 tile, BK=32,
// global_load_lds width=16 into linear LDS, 2 barriers/K-step.
// XCD-chunked block swizzle: same-m-panel blocks land on one XCD (L2 reuse).
// EPI=0: bf16 C.  EPI=1: fp32 C = acc + resid.  EPI=2: fp32 partial per
// blockIdx.z (split-K=2), written to Cout + z*M*N.
// ---------------------------------------------------------------------------
template<int EPI>
__global__ __launch_bounds__(256)
void gemm_kernel(const bf16_t* __restrict__ A, const bf16_t* __restrict__ Bt,
                 const bf16_t* __restrict__ Bt2, int splitMy,
                 void* Cout, const float* resid, int M, int N, int K)
{
    __shared__ bf16_t As[128][32];
    __shared__ bf16_t Bs[128][32];
    const int tid = threadIdx.x;
    const int l = tid & 63, w = tid >> 6;
    const int wr = w >> 1, wc = w & 1;

    // XCD-chunked swizzle (bijective when grid multiple of 8)
    const int nbxy = gridDim.x * gridDim.y;
    int bid = blockIdx.y * gridDim.x + blockIdx.x;
    if ((nbxy & 7) == 0) bid = (bid & 7) * (nbxy >> 3) + (bid >> 3);
    const int bx = bid % gridDim.x, by = bid / gridDim.x;

    const int m0 = by * 128, n0 = bx * 128;
    const bf16_t* Bsel = (by < splitMy) ? Bt : Bt2;

    int kbeg = 0, kend = K;
    if constexpr (EPI == 2) { const int half = K >> 1; kbeg = blockIdx.z * half; kend = kbeg + half; }

    const int srow = l >> 2;
    const int scol = (l & 3) * 8;
    const bf16_t* Ag0 = A    + (size_t)(m0 + w * 32 + srow) * K + scol;
    const bf16_t* Ag1 = Ag0 + (size_t)16 * K;
    const bf16_t* Bg0 = Bsel + (size_t)(n0 + w * 32 + srow) * K + scol;
    const bf16_t* Bg1 = Bg0 + (size_t)16 * K;
    char* Asb = (char*)&As[0][0] + w * 2048;
    char* Bsb = (char*)&Bs[0][0] + w * 2048;

    f32x4 acc[4][4];
    const f32x4 zero = {0.f, 0.f, 0.f, 0.f};
#pragma unroll
    for (int i = 0; i < 4; i++)
#pragma unroll
        for (int j = 0; j < 4; j++) acc[i][j] = zero;

    const int fr = l & 15;
    const int fk = (l >> 4) * 8;

    for (int k0 = kbeg; k0 < kend; k0 += 32) {
        gl_lds16(Ag0 + k0, Asb);
        gl_lds16(Ag1 + k0, Asb + 1024);
        gl_lds16(Bg0 + k0, Bsb);
        gl_lds16(Bg1 + k0, Bsb + 1024);
        __syncthreads();

        bf16x8 af[4], bv[4];
#pragma unroll
        for (int i = 0; i < 4; i++) af[i] = *(const bf16x8*)&As[wr * 64 + i * 16 + fr][fk];
#pragma unroll
        for (int i = 0; i < 4; i++) bv[i] = *(const bf16x8*)&Bs[wc * 64 + i * 16 + fr][fk];
        __builtin_amdgcn_s_setprio(1);
#pragma unroll
        for (int mi = 0; mi < 4; mi++)
#pragma unroll
            for (int ni = 0; ni < 4; ni++)
                acc[mi][ni] = __builtin_amdgcn_mfma_f32_16x16x32_bf16(af[mi], bv[ni], acc[mi][ni], 0, 0, 0);
        __builtin_amdgcn_s_setprio(0);
        __syncthreads();
    }

    const int orow = (l >> 4) * 4;
    const int ocol = l & 15;
#pragma unroll
    for (int mi = 0; mi < 4; mi++)
#pragma unroll
        for (int ni = 0; ni < 4; ni++)
#pragma unroll
            for (int j = 0; j < 4; j++) {
                int row = m0 + wr * 64 + mi * 16 + orow + j;
                int col = n0 + wc * 64 + ni * 16 + ocol;
                size_t idx = (size_t)row * N + col;
                if constexpr (EPI == 0) {
                    ((bf16_t*)Cout)[idx] = (bf16_t)acc[mi][ni][j];
                } else if constexpr (EPI == 1) {
                    ((float*)Cout)[idx] = acc[mi][ni][j] + resid[idx];
                } else {
                    ((float*)Cout)[(size_t)blockIdx.z * M * N + idx] = acc[mi][ni][j];
                }
            }
}

// ---------------------------------------------------------------------------
// Causal flash attention.  Q/K/O: [B*S][1024] bf16 (head h = cols h*64..+64).
// Vt: [B][1024][2048] bf16 (pre-transposed V).
// 1D grid 1024 blocks.  XCD-chunked: XCD x owns heads 4x..4x+3 entirely (K/V
// L2-resident).  Within a head, zigzag q pairing balances per-CU work.
// 4 waves/block; wave w owns q rows q0+w*16..+16.  KVBLK=64, T14 issue-early,
// exp2 softmax, defer-max (T13), setprio (T5).
// ---------------------------------------------------------------------------
__global__ __launch_bounds__(256)
void fa_kernel(const bf16_t* __restrict__ Q, const bf16_t* __restrict__ K,
               const bf16_t* __restrict__ Vt, bf16_t* __restrict__ O)
{
    __shared__ bf16_t Ks[64][72];
    __shared__ bf16_t Vs[64][72];
    __shared__ bf16_t Ps[4][16][72];

    const int tid = threadIdx.x;
    const int l = tid & 63, w = tid >> 6;

    // XCD-chunked head mapping + zigzag q
    const int bid = blockIdx.x;
    const int logical = (bid & 7) * 128 + (bid >> 3);  // XCD gets 128 consecutive
    const int bh = logical >> 5;                        // 4 heads per XCD
    const int jq = logical & 31;
    const int qb = (jq & 1) ? (31 - (jq >> 1)) : (jq >> 1);
    const int b = bh >> 4, h = bh & 15;
    const int q0 = qb * 64;

    const bf16_t* Qp = Q + (size_t)b * S_LEN * D_DIM + h * DH;
    const bf16_t* Kp = K + (size_t)b * S_LEN * D_DIM + h * DH;
    const bf16_t* Vp = Vt + (size_t)b * D_DIM * S_LEN + (size_t)h * DH * S_LEN;

    const int fr = l & 15, fg = l >> 4, fk = fg * 8;

    bf16x8 qf[2];
#pragma unroll
    for (int ks = 0; ks < 2; ks++)
        qf[ks] = *(const bf16x8*)(Qp + (size_t)(q0 + w * 16 + fr) * D_DIM + ks * 32 + fk);

    const f32x4 zero = {0.f, 0.f, 0.f, 0.f};
    f32x4 o[4];
    float m_r[4], l_r[4];
#pragma unroll
    for (int j = 0; j < 4; j++) { o[j] = zero; m_r[j] = -1e30f; l_r[j] = 0.f; }

    const int srow = tid >> 2;
    const int scol = (tid & 3) * 16;
    const bf16_t* Kst = Kp + (size_t)srow * D_DIM + scol;
    const bf16_t* Vst = Vp + (size_t)srow * S_LEN + scol;

    const int nt = q0 / 64 + 1;
    const float C_LOG2 = 0.125f * 1.44269504f;   // 1/sqrt(DH) * log2(e)

    // prologue: issue loads for tile 0
    uint4 kva = *(const uint4*)(Kst);
    uint4 kvb = *(const uint4*)(Kst + 8);
    uint4 vva = *(const uint4*)(Vst);
    uint4 vvb = *(const uint4*)(Vst + 8);

    for (int t = 0; t < nt; t++) {
        const int k0 = t * 64;
        __syncthreads();              // previous tile's reads complete
        *(uint4*)&Ks[srow][scol]     = kva;
        *(uint4*)&Ks[srow][scol + 8] = kvb;
        *(uint4*)&Vs[srow][scol]     = vva;
        *(uint4*)&Vs[srow][scol + 8] = vvb;
        __syncthreads();

        if (t + 1 < nt) {             // T14: issue next tile's loads now
            const int kn = k0 + 64;
            kva = *(const uint4*)(Kst + (size_t)kn * D_DIM);
            kvb = *(const uint4*)(Kst + (size_t)kn * D_DIM + 8);
            vva = *(const uint4*)(Vst + kn);
            vvb = *(const uint4*)(Vst + kn + 8);
        }

        const int wq_hi = q0 + w * 16 + 15;
        if (k0 > wq_hi) continue;

        // ---- QK^T: 16 q-rows x 64 keys ----
        f32x4 sc[4];
#pragma unroll
        for (int ni = 0; ni < 4; ni++) sc[ni] = zero;
        __builtin_amdgcn_s_setprio(1);
#pragma unroll
        for (int ks = 0; ks < 2; ks++) {
#pragma unroll
            for (int ni = 0; ni < 4; ni++) {
                bf16x8 kf = *(const bf16x8*)&Ks[ni * 16 + fr][ks * 32 + fk];
                sc[ni] = __builtin_amdgcn_mfma_f32_16x16x32_bf16(qf[ks], kf, sc[ni], 0, 0, 0);
            }
        }
        __builtin_amdgcn_s_setprio(0);

        // ---- scale to log2 domain + causal mask ----
        float p[4][4];
#pragma unroll
        for (int ni = 0; ni < 4; ni++) {
            const int key = k0 + ni * 16 + fr;
#pragma unroll
            for (int j = 0; j < 4; j++) {
                const int qg = q0 + w * 16 + fg * 4 + j;
                p[ni][j] = (key <= qg) ? sc[ni][j] * C_LOG2 : -1e30f;
            }
        }

        // ---- online softmax (exp2 domain), defer-max (T13) ----
#pragma unroll
        for (int j = 0; j < 4; j++) {
            float rmax = fmaxf(fmaxf(p[0][j], p[1][j]), fmaxf(p[2][j], p[3][j]));
#pragma unroll
            for (int d = 1; d < 16; d <<= 1) rmax = fmaxf(rmax, __shfl_xor(rmax, d));
            if (rmax > m_r[j] + 8.f) {         // rescale only on real growth
                float scale = exp2f(m_r[j] - rmax);
                l_r[j] *= scale;
#pragma unroll
                for (int nc = 0; nc < 4; nc++) o[nc][j] *= scale;
                m_r[j] = rmax;
            }
            float rsum = 0.f;
#pragma unroll
            for (int ni = 0; ni < 4; ni++) {
                float e = exp2f(p[ni][j] - m_r[j]);   // bounded by 2^8
                p[ni][j] = e; rsum += e;
            }
#pragma unroll
            for (int d = 1; d < 16; d <<= 1) rsum += __shfl_xor(rsum, d);
            l_r[j] += rsum;
        }

        // ---- P -> A-layout via per-wave LDS bounce ----
#pragma unroll
        for (int ni = 0; ni < 4; ni++)
#pragma unroll
            for (int j = 0; j < 4; j++)
                Ps[w][fg * 4 + j][ni * 16 + fr] = (bf16_t)p[ni][j];

        // ---- PV ----
        __builtin_amdgcn_s_setprio(1);
#pragma unroll
        for (int ks = 0; ks < 2; ks++) {
            bf16x8 pa = *(const bf16x8*)&Ps[w][fr][ks * 32 + fk];
#pragma unroll
            for (int nc = 0; nc < 4; nc++) {
                bf16x8 vf = *(const bf16x8*)&Vs[nc * 16 + fr][ks * 32 + fk];
                o[nc] = __builtin_amdgcn_mfma_f32_16x16x32_bf16(pa, vf, o[nc], 0, 0, 0);
            }
        }
        __builtin_amdgcn_s_setprio(0);
    }

    // ---- epilogue ----
#pragma unroll
    for (int j = 0; j < 4; j++) {
        const float inv = 1.f / l_r[j];
        const int q = q0 + w * 16 + fg * 4 + j;
        bf16_t* op = O + (size_t)(b * S_LEN + q) * D_DIM + h * DH;
#pragma unroll
        for (int nc = 0; nc < 4; nc++)
            op[nc * 16 + fr] = (bf16_t)(o[nc][j] * inv);
    }
}

// ---------------------------------------------------------------------------
extern "C" void kernel_launch(void* const* d_in, const int* in_sizes, int n_in,
                              void* d_out, int out_size, void* d_ws, size_t ws_size,
                              hipStream_t stream)
{
    const float* x      = (const float*)d_in[0];
    const float* fqk_wQ = (const float*)d_in[1];
    const float* fqk_wK = (const float*)d_in[2];
    const float* fv_w   = (const float*)d_in[3];
    const float* rqk_wQ = (const float*)d_in[4];
    const float* rqk_wK = (const float*)d_in[5];
    const float* rv_w   = (const float*)d_in[6];
    const float* fkn_w  = (const float*)d_in[7];
    const float* rkn_w  = (const float*)d_in[8];
    const float* f_qk   = (const float*)d_in[9];
    const float* f_v    = (const float*)d_in[10];
    const float* r_qk   = (const float*)d_in[11];
    const float* r_v    = (const float*)d_in[12];
    const float* f_know = (const float*)d_in[13];
    const float* r_know = (const float*)d_in[14];
    const float* W_O    = (const float*)d_in[15];
    const float* ln1g   = (const float*)d_in[16];
    const float* ln1b   = (const float*)d_in[17];
    const float* ln2g   = (const float*)d_in[18];
    const float* ln2b   = (const float*)d_in[19];
    float* out_f = (float*)d_out;
    (void)ws_size; (void)in_sizes; (void)n_in; (void)out_size;

    // ---- workspace layout (reused slots) ----
    char* ws = (char*)d_ws;
    const size_t MB = 1024 * 1024;
    bf16_t* rqkT   = (bf16_t*)(ws + 0 * MB);    // [1024][2048]  4MB
    bf16_t* rvT    = (bf16_t*)(ws + 4 * MB);    // [1024][2048]  4MB
    bf16_t* rknT   = (bf16_t*)(ws + 8 * MB);    // [1024][1024]  2MB
    bf16_t* woB    = (bf16_t*)(ws + 10 * MB);   // [1024][1024]  2MB
    bf16_t* fknT   = (bf16_t*)(ws + 12 * MB);   // [1024][1024]  2MB
    bf16_t* buf_nx = (bf16_t*)(ws + 14 * MB);   // 8MB: nx -> Vt -> nx2
    bf16_t* buf_y  = (bf16_t*)(ws + 22 * MB);   // 32MB: y[4096][4096] -> QKV[12288][1024]
    char*   buf_s  = ws + 54 * MB;              // 48MB
    bf16_t* fqkT   = (bf16_t*)(buf_s);               // [2048][1024] 4MB (pre-ws only)
    bf16_t* fvT    = (bf16_t*)(buf_s + 4 * MB);      // contiguous -> N=4096 B
    bf16_t* s_q    = (bf16_t*)(buf_s);               // [12288][2048] grouped A
    bf16_t* s_k    = (bf16_t*)(buf_s) + (size_t)4096 * 2048;
    bf16_t* s_v    = (bf16_t*)(buf_s) + (size_t)8192 * 2048;
    bf16_t* attn   = (bf16_t*)(buf_s);               // [4096][1024] 8MB
    float*  P0     = (float*)(buf_s + 16 * MB);      // W_O split-K partials 2x16MB
    float*  P0k    = (float*)(buf_s);                // know split-K partials
    float*  P1k    = (float*)(buf_s + 16 * MB);
    bf16_t* sk2    = (bf16_t*)(buf_s + 32 * MB);     // [4096][1024] 8MB
    bf16_t* Qb     = buf_y;                          // QKV contiguous [12288][1024]
    bf16_t* Kb     = buf_y + (size_t)4096 * 1024;
    bf16_t* Vb     = buf_y + (size_t)8192 * 1024;
    bf16_t* Vt     = buf_nx;                         // [2][1024][2048]

    const dim3 blk256(256), blkT(32, 8);

    // ---- weight conversion ----
    tcast_kernel<<<dim3(R_DIM / 32, D_DIM / 32, N_NEU), blkT, 0, stream>>>(f_qk, fqkT, D_DIM, R_DIM);
    tcast_kernel<<<dim3(R_DIM / 32, D_DIM / 32, N_NEU), blkT, 0, stream>>>(f_v, fvT, D_DIM, R_DIM);
    tcast_kernel<<<dim3(KR_DIM / 32, D_DIM / 32, N_NEU), blkT, 0, stream>>>(f_know, fknT, D_DIM, KR_DIM);
    tcast_kernel<<<dim3(D_DIM / 32, 2048 / 32, 1), blkT, 0, stream>>>(r_qk, rqkT, 2048, D_DIM);
    tcast_kernel<<<dim3(D_DIM / 32, 2048 / 32, 1), blkT, 0, stream>>>(r_v, rvT, 2048, D_DIM);
    tcast_kernel<<<dim3(D_DIM / 32, 1024 / 32, 1), blkT, 0, stream>>>(r_know, rknT, 1024, D_DIM);
    cast_kernel<<<dim3(1024 * 1024 / 4 / 256), blk256, 0, stream>>>(W_O, woB, 1024 * 1024 / 4);

    // ---- LN1 ----
    ln_kernel<<<dim3(ROWS), blk256, 0, stream>>>(x, ln1g, ln1b, buf_nx);

    // ---- fused feature GEMM: y[4096][4096] = nx @ [fqkT;fvT]^T ----
    gemm_kernel<0><<<dim3(32, 32), blk256, 0, stream>>>(buf_nx, fqkT, fqkT, 1 << 30, buf_y, nullptr, 4096, 4096, 1024);

    // ---- fused weighted sums -> sq|sk|sv [12288][2048] ----
    wsf_kernel<<<dim3(ROWS), blk256, 0, stream>>>(buf_y, fqk_wQ, rqk_wQ, fqk_wK, rqk_wK, fv_w, rv_w, s_q, s_k, s_v);

    // ---- grouped restore GEMM: QKV[12288][1024] (768 blocks, B-select) ----
    gemm_kernel<0><<<dim3(8, 96), blk256, 0, stream>>>((bf16_t*)buf_s, rqkT, rvT, 64, buf_y, nullptr, 12288, 1024, 2048);

    // ---- V -> Vt ----
    tbf_kernel<<<dim3(D_DIM / 32, S_LEN / 32, B_DIM), blkT, 0, stream>>>(Vb, Vt, S_LEN, D_DIM);

    // ---- attention (1024 blocks, 1D grid) ----
    fa_kernel<<<dim3(1024), blk256, 0, stream>>>(Qb, Kb, Vt, attn);

    // ---- W_O split-K=2: partials P0/P1 (512 blocks) ----
    gemm_kernel<2><<<dim3(8, 32, 2), blk256, 0, stream>>>(attn, woB, woB, 1 << 30, P0, nullptr, 4096, 1024, 1024);

    // ---- LN2 fused: d_out = x + P0 + P1; nx2 = LN(d_out) ----
    ln2x_kernel<<<dim3(ROWS), blk256, 0, stream>>>(x, P0, P0 + (size_t)4096 * 1024, ln2g, ln2b, out_f, buf_nx);

    // ---- know feature split-K=2: partials P0k/P1k (512 blocks) ----
    gemm_kernel<2><<<dim3(8, 32, 2), blk256, 0, stream>>>(buf_nx, fknT, fknT, 1 << 30, P0k, nullptr, 4096, 1024, 1024);

    // ---- know ws (fused reduce) -> sk2 ----
    ws2_kernel<<<dim3(ROWS / 2), blk256, 0, stream>>>(P0k, P1k, fkn_w, rkn_w, sk2);

    // ---- out = sk2 @ rknT^T + x2 -> d_out ----
    gemm_kernel<1><<<dim3(8, 32), blk256, 0, stream>>>(sk2, rknT, rknT, 1 << 30, d_out, out_f, 4096, 1024, 1024);
}

// Round 5
// 347.148 us; speedup vs baseline: 1.7394x; 1.1216x over previous
//
#include <hip/hip_runtime.h>
#include <hip/hip_bf16.h>

// ---------------------------------------------------------------------------
// DAWN block on MI355X.  Round 5: fa per-CU load balance.
//  - fa: closed-form balanced (head,qb) mapping — every CU gets exactly 66
//    tile-units (qb set {t,15-t,16+t,31-t}), one head per CU, XCD-chunked.
//  - everything else unchanged from round 4.
// ---------------------------------------------------------------------------

typedef __bf16 bf16_t;
typedef __bf16 bf16x8 __attribute__((ext_vector_type(8)));
typedef float f32x4 __attribute__((ext_vector_type(4)));

#define B_DIM 2
#define S_LEN 2048
#define D_DIM 1024
#define H_NUM 16
#define DH 64
#define N_NEU 8
#define R_DIM 256
#define KR_DIM 128
#define ROWS (B_DIM * S_LEN)   // 4096

static __device__ __forceinline__ void gl_lds16(const void* g, void* l)
{
    __builtin_amdgcn_global_load_lds(
        (__attribute__((address_space(1))) void*)(g),
        (__attribute__((address_space(3))) void*)(l), 16, 0, 0);
}

// ---------------------------------------------------------------------------
// Batched transpose-cast: in[z][I][J] f32 -> out[z][J][I] bf16.  block (32,8)
// ---------------------------------------------------------------------------
__global__ __launch_bounds__(256)
void tcast_kernel(const float* __restrict__ in, bf16_t* __restrict__ out, int I, int J)
{
    __shared__ float t[32][33];
    const int bJ = blockIdx.x * 32, bI = blockIdx.y * 32;
    const size_t boff = (size_t)blockIdx.z * I * J;
    const int tx = threadIdx.x, ty = threadIdx.y;
#pragma unroll
    for (int i = 0; i < 4; i++)
        t[ty * 4 + i][tx] = in[boff + (size_t)(bI + ty * 4 + i) * J + bJ + tx];
    __syncthreads();
#pragma unroll
    for (int i = 0; i < 4; i++)
        out[boff + (size_t)(bJ + ty * 4 + i) * I + bI + tx] = (bf16_t)t[tx][ty * 4 + i];
}

// bf16 transpose: in[z][I][J] -> out[z][J][I].  block (32,8)
__global__ __launch_bounds__(256)
void tbf_kernel(const bf16_t* __restrict__ in, bf16_t* __restrict__ out, int I, int J)
{
    __shared__ bf16_t t[32][33];
    const int bJ = blockIdx.x * 32, bI = blockIdx.y * 32;
    const size_t boff = (size_t)blockIdx.z * I * J;
    const int tx = threadIdx.x, ty = threadIdx.y;
#pragma unroll
    for (int i = 0; i < 4; i++)
        t[ty * 4 + i][tx] = in[boff + (size_t)(bI + ty * 4 + i) * J + bJ + tx];
    __syncthreads();
#pragma unroll
    for (int i = 0; i < 4; i++)
        out[boff + (size_t)(bJ + ty * 4 + i) * I + bI + tx] = t[tx][ty * 4 + i];
}

// plain cast fp32 -> bf16 (vectorized by 4)
__global__ __launch_bounds__(256)
void cast_kernel(const float* __restrict__ in, bf16_t* __restrict__ out, int n4)
{
    int i = blockIdx.x * 256 + threadIdx.x;
    if (i < n4) {
        float4 v = ((const float4*)in)[i];
        bf16_t* op = out + (size_t)i * 4;
        op[0] = (bf16_t)v.x; op[1] = (bf16_t)v.y; op[2] = (bf16_t)v.z; op[3] = (bf16_t)v.w;
    }
}

// ---------------------------------------------------------------------------
// LayerNorm over D=1024, one row per block. fp32 in, bf16 out.
// ---------------------------------------------------------------------------
__global__ __launch_bounds__(256)
void ln_kernel(const float* __restrict__ x, const float* __restrict__ g,
               const float* __restrict__ beta, bf16_t* __restrict__ out)
{
    __shared__ float red[4];
    const int row = blockIdx.x;
    const int tid = threadIdx.x;
    float4 v = *(const float4*)&x[(size_t)row * D_DIM + tid * 4];

    float s = v.x + v.y + v.z + v.w;
#pragma unroll
    for (int o = 32; o; o >>= 1) s += __shfl_down(s, o);
    if ((tid & 63) == 0) red[tid >> 6] = s;
    __syncthreads();
    float mean = (red[0] + red[1] + red[2] + red[3]) * (1.f / D_DIM);
    __syncthreads();

    float dx = v.x - mean, dy = v.y - mean, dz = v.z - mean, dw = v.w - mean;
    float q = dx * dx + dy * dy + dz * dz + dw * dw;
#pragma unroll
    for (int o = 32; o; o >>= 1) q += __shfl_down(q, o);
    if ((tid & 63) == 0) red[tid >> 6] = q;
    __syncthreads();
    float var = (red[0] + red[1] + red[2] + red[3]) * (1.f / D_DIM);
    float rstd = rsqrtf(var + 1e-5f);

    float4 gv = *(const float4*)&g[tid * 4];
    float4 bv = *(const float4*)&beta[tid * 4];
    bf16_t* op = out + (size_t)row * D_DIM + tid * 4;
    op[0] = (bf16_t)(dx * rstd * gv.x + bv.x);
    op[1] = (bf16_t)(dy * rstd * gv.y + bv.y);
    op[2] = (bf16_t)(dz * rstd * gv.z + bv.z);
    op[3] = (bf16_t)(dw * rstd * gv.w + bv.w);
}

// ---------------------------------------------------------------------------
// LN2 with fused split-K reduce + residual:  sum = x + P0 + P1 -> outf (fp32),
// then LN(sum) -> bf16 outn.
// ---------------------------------------------------------------------------
__global__ __launch_bounds__(256)
void ln2x_kernel(const float* __restrict__ x, const float* __restrict__ P0,
                 const float* __restrict__ P1, const float* __restrict__ g,
                 const float* __restrict__ beta, float* __restrict__ outf,
                 bf16_t* __restrict__ outn)
{
    __shared__ float red[4];
    const int row = blockIdx.x;
    const int tid = threadIdx.x;
    const size_t base = (size_t)row * D_DIM + tid * 4;
    float4 v  = *(const float4*)&x[base];
    float4 p0 = *(const float4*)&P0[base];
    float4 p1 = *(const float4*)&P1[base];
    v.x += p0.x + p1.x; v.y += p0.y + p1.y; v.z += p0.z + p1.z; v.w += p0.w + p1.w;
    *(float4*)&outf[base] = v;

    float s = v.x + v.y + v.z + v.w;
#pragma unroll
    for (int o = 32; o; o >>= 1) s += __shfl_down(s, o);
    if ((tid & 63) == 0) red[tid >> 6] = s;
    __syncthreads();
    float mean = (red[0] + red[1] + red[2] + red[3]) * (1.f / D_DIM);
    __syncthreads();

    float dx = v.x - mean, dy = v.y - mean, dz = v.z - mean, dw = v.w - mean;
    float q = dx * dx + dy * dy + dz * dz + dw * dw;
#pragma unroll
    for (int o = 32; o; o >>= 1) q += __shfl_down(q, o);
    if ((tid & 63) == 0) red[tid >> 6] = q;
    __syncthreads();
    float var = (red[0] + red[1] + red[2] + red[3]) * (1.f / D_DIM);
    float rstd = rsqrtf(var + 1e-5f);

    float4 gv = *(const float4*)&g[tid * 4];
    float4 bv = *(const float4*)&beta[tid * 4];
    bf16_t* op = outn + base;
    op[0] = (bf16_t)(dx * rstd * gv.x + bv.x);
    op[1] = (bf16_t)(dy * rstd * gv.y + bv.y);
    op[2] = (bf16_t)(dz * rstd * gv.z + bv.z);
    op[3] = (bf16_t)(dw * rstd * gv.w + bv.w);
}

// ---------------------------------------------------------------------------
// Fused weighted-sum for Q/K/V: reads y row once, writes sq, sk, sv.
// y: [4096][4096] (cols 0..2047 = qk-neurons, 2048..4095 = v-neurons).
// ---------------------------------------------------------------------------
__global__ __launch_bounds__(256)
void wsf_kernel(const bf16_t* __restrict__ y,
                const float* __restrict__ wfQ, const float* __restrict__ wrQ,
                const float* __restrict__ wfK, const float* __restrict__ wrK,
                const float* __restrict__ wfV, const float* __restrict__ wrV,
                bf16_t* __restrict__ sq, bf16_t* __restrict__ sk, bf16_t* __restrict__ sv)
{
    const int r = threadIdx.x;     // 0..255
    const int row = blockIdx.x;
    const bf16_t* yrow = y + (size_t)row * 4096;
    const float* fQ = wfQ + row * N_NEU;
    const float* fK = wfK + row * N_NEU;
    const float* fV = wfV + row * N_NEU;
    float aQ = 0.f, aK = 0.f, aV = 0.f;
#pragma unroll
    for (int n = 0; n < N_NEU; n++) {
        float yq = (float)yrow[n * R_DIM + r];
        float yv = (float)yrow[2048 + n * R_DIM + r];
        aQ += fQ[n] * yq;
        aK += fK[n] * yq;
        aV += fV[n] * yv;
    }
    const float* rQ = wrQ + row * N_NEU;
    const float* rK = wrK + row * N_NEU;
    const float* rV = wrV + row * N_NEU;
    const size_t rb = (size_t)row * 2048;
#pragma unroll
    for (int n = 0; n < N_NEU; n++) {
        sq[rb + n * R_DIM + r] = (bf16_t)(rQ[n] * aQ);
        sk[rb + n * R_DIM + r] = (bf16_t)(rK[n] * aK);
        sv[rb + n * R_DIM + r] = (bf16_t)(rV[n] * aV);
    }
}

// know-path ws with fused split-K reduce: y = P0+P1 (fp32 partials), KR=128.
__global__ __launch_bounds__(256)
void ws2_kernel(const float* __restrict__ P0, const float* __restrict__ P1,
                const float* __restrict__ wf, const float* __restrict__ wr,
                bf16_t* __restrict__ sout)
{
    const int lr = threadIdx.x >> 7;
    const int r  = threadIdx.x & 127;
    const int row = blockIdx.x * 2 + lr;
    const size_t rb = (size_t)row * (N_NEU * KR_DIM);
    const float* wfp = wf + row * N_NEU;
    const float* wrp = wr + row * N_NEU;
    float acc = 0.f;
#pragma unroll
    for (int n = 0; n < N_NEU; n++) {
        size_t i = rb + n * KR_DIM + r;
        acc += wfp[n] * (P0[i] + P1[i]);
    }
    bf16_t* srow = sout + rb;
#pragma unroll
    for (int n = 0; n < N_NEU; n++) srow[n * KR_DIM + r] = (bf16_t)(wrp[n] * acc);
}

// ---------------------------------------------------------------------------
// GEMM (m97 structure): C[M,N] = A[M,K] @ Bsel[N,K]^T.  128x128 tile, BK=32,
// global_load_lds width=16 into linear LDS, 2 barriers/K-step.
// XCD-chunked block swizzle.  EPI=0: bf16 C.  EPI=1: fp32 C = acc + resid.
// EPI=2: fp32 partial per blockIdx.z (split-K=2).
// ---------------------------------------------------------------------------
template<int EPI>
__global__ __launch_bounds__(256)
void gemm_kernel(const bf16_t* __restrict__ A, const bf16_t* __restrict__ Bt,
                 const bf16_t* __restrict__ Bt2, int splitMy,
                 void* Cout, const float* resid, int M, int N, int K)
{
    __shared__ bf16_t As[128][32];
    __shared__ bf16_t Bs[128][32];
    const int tid = threadIdx.x;
    const int l = tid & 63, w = tid >> 6;
    const int wr = w >> 1, wc = w & 1;

    // XCD-chunked swizzle (bijective when grid multiple of 8)
    const int nbxy = gridDim.x * gridDim.y;
    int bid = blockIdx.y * gridDim.x + blockIdx.x;
    if ((nbxy & 7) == 0) bid = (bid & 7) * (nbxy >> 3) + (bid >> 3);
    const int bx = bid % gridDim.x, by = bid / gridDim.x;

    const int m0 = by * 128, n0 = bx * 128;
    const bf16_t* Bsel = (by < splitMy) ? Bt : Bt2;

    int kbeg = 0, kend = K;
    if constexpr (EPI == 2) { const int half = K >> 1; kbeg = blockIdx.z * half; kend = kbeg + half; }

    const int srow = l >> 2;
    const int scol = (l & 3) * 8;
    const bf16_t* Ag0 = A    + (size_t)(m0 + w * 32 + srow) * K + scol;
    const bf16_t* Ag1 = Ag0 + (size_t)16 * K;
    const bf16_t* Bg0 = Bsel + (size_t)(n0 + w * 32 + srow) * K + scol;
    const bf16_t* Bg1 = Bg0 + (size_t)16 * K;
    char* Asb = (char*)&As[0][0] + w * 2048;
    char* Bsb = (char*)&Bs[0][0] + w * 2048;

    f32x4 acc[4][4];
    const f32x4 zero = {0.f, 0.f, 0.f, 0.f};
#pragma unroll
    for (int i = 0; i < 4; i++)
#pragma unroll
        for (int j = 0; j < 4; j++) acc[i][j] = zero;

    const int fr = l & 15;
    const int fk = (l >> 4) * 8;

    for (int k0 = kbeg; k0 < kend; k0 += 32) {
        gl_lds16(Ag0 + k0, Asb);
        gl_lds16(Ag1 + k0, Asb + 1024);
        gl_lds16(Bg0 + k0, Bsb);
        gl_lds16(Bg1 + k0, Bsb + 1024);
        __syncthreads();

        bf16x8 af[4], bv[4];
#pragma unroll
        for (int i = 0; i < 4; i++) af[i] = *(const bf16x8*)&As[wr * 64 + i * 16 + fr][fk];
#pragma unroll
        for (int i = 0; i < 4; i++) bv[i] = *(const bf16x8*)&Bs[wc * 64 + i * 16 + fr][fk];
        __builtin_amdgcn_s_setprio(1);
#pragma unroll
        for (int mi = 0; mi < 4; mi++)
#pragma unroll
            for (int ni = 0; ni < 4; ni++)
                acc[mi][ni] = __builtin_amdgcn_mfma_f32_16x16x32_bf16(af[mi], bv[ni], acc[mi][ni], 0, 0, 0);
        __builtin_amdgcn_s_setprio(0);
        __syncthreads();
    }

    const int orow = (l >> 4) * 4;
    const int ocol = l & 15;
#pragma unroll
    for (int mi = 0; mi < 4; mi++)
#pragma unroll
        for (int ni = 0; ni < 4; ni++)
#pragma unroll
            for (int j = 0; j < 4; j++) {
                int row = m0 + wr * 64 + mi * 16 + orow + j;
                int col = n0 + wc * 64 + ni * 16 + ocol;
                size_t idx = (size_t)row * N + col;
                if constexpr (EPI == 0) {
                    ((bf16_t*)Cout)[idx] = (bf16_t)acc[mi][ni][j];
                } else if constexpr (EPI == 1) {
                    ((float*)Cout)[idx] = acc[mi][ni][j] + resid[idx];
                } else {
                    ((float*)Cout)[(size_t)blockIdx.z * M * N + idx] = acc[mi][ni][j];
                }
            }
}

// ---------------------------------------------------------------------------
// Causal flash attention.  Q/K/O: [B*S][1024] bf16 (head h = cols h*64..+64).
// Vt: [B][1024][2048] bf16 (pre-transposed V).
// 1D grid 1024 blocks.  Balanced XCD-chunked mapping:
//   xcd = bid&7, slot = bid>>3 (0..127), head = slot&3, j = slot>>2,
//   qb = 8u + (u&1 ? 7-t : t) with t=j&7, u=j>>3.
// A CU's 4 resident blocks (slots c,c+32,c+64,c+96) get qb {t,15-t,16+t,31-t}
// -> exactly 66 tile-units per CU, one head per CU, K/V L2-resident per XCD.
// 4 waves/block; wave w owns q rows q0+w*16..+16.  KVBLK=64, T14 issue-early,
// exp2 softmax, defer-max (T13), setprio (T5).
// ---------------------------------------------------------------------------
__global__ __launch_bounds__(256)
void fa_kernel(const bf16_t* __restrict__ Q, const bf16_t* __restrict__ K,
               const bf16_t* __restrict__ Vt, bf16_t* __restrict__ O)
{
    __shared__ bf16_t Ks[64][72];
    __shared__ bf16_t Vs[64][72];
    __shared__ bf16_t Ps[4][16][72];

    const int tid = threadIdx.x;
    const int l = tid & 63, w = tid >> 6;

    // balanced XCD-chunked mapping
    const int bid = blockIdx.x;
    const int xcd  = bid & 7;
    const int slot = bid >> 3;          // 0..127
    const int head = slot & 3;          // 4 heads per XCD; CU-constant
    const int j5   = slot >> 2;         // 0..31
    const int t5   = j5 & 7, u5 = j5 >> 3;
    const int qb   = 8 * u5 + ((u5 & 1) ? (7 - t5) : t5);
    const int bh   = xcd * 4 + head;
    const int b = bh >> 4, h = bh & 15;
    const int q0 = qb * 64;

    const bf16_t* Qp = Q + (size_t)b * S_LEN * D_DIM + h * DH;
    const bf16_t* Kp = K + (size_t)b * S_LEN * D_DIM + h * DH;
    const bf16_t* Vp = Vt + (size_t)b * D_DIM * S_LEN + (size_t)h * DH * S_LEN;

    const int fr = l & 15, fg = l >> 4, fk = fg * 8;

    bf16x8 qf[2];
#pragma unroll
    for (int ks = 0; ks < 2; ks++)
        qf[ks] = *(const bf16x8*)(Qp + (size_t)(q0 + w * 16 + fr) * D_DIM + ks * 32 + fk);

    const f32x4 zero = {0.f, 0.f, 0.f, 0.f};
    f32x4 o[4];
    float m_r[4], l_r[4];
#pragma unroll
    for (int j = 0; j < 4; j++) { o[j] = zero; m_r[j] = -1e30f; l_r[j] = 0.f; }

    const int srow = tid >> 2;
    const int scol = (tid & 3) * 16;
    const bf16_t* Kst = Kp + (size_t)srow * D_DIM + scol;
    const bf16_t* Vst = Vp + (size_t)srow * S_LEN + scol;

    const int nt = q0 / 64 + 1;
    const float C_LOG2 = 0.125f * 1.44269504f;   // 1/sqrt(DH) * log2(e)

    // prologue: issue loads for tile 0
    uint4 kva = *(const uint4*)(Kst);
    uint4 kvb = *(const uint4*)(Kst + 8);
    uint4 vva = *(const uint4*)(Vst);
    uint4 vvb = *(const uint4*)(Vst + 8);

    for (int t = 0; t < nt; t++) {
        const int k0 = t * 64;
        __syncthreads();              // previous tile's reads complete
        *(uint4*)&Ks[srow][scol]     = kva;
        *(uint4*)&Ks[srow][scol + 8] = kvb;
        *(uint4*)&Vs[srow][scol]     = vva;
        *(uint4*)&Vs[srow][scol + 8] = vvb;
        __syncthreads();

        if (t + 1 < nt) {             // T14: issue next tile's loads now
            const int kn = k0 + 64;
            kva = *(const uint4*)(Kst + (size_t)kn * D_DIM);
            kvb = *(const uint4*)(Kst + (size_t)kn * D_DIM + 8);
            vva = *(const uint4*)(Vst + kn);
            vvb = *(const uint4*)(Vst + kn + 8);
        }

        // ---- QK^T: 16 q-rows x 64 keys ----
        f32x4 sc[4];
#pragma unroll
        for (int ni = 0; ni < 4; ni++) sc[ni] = zero;
        __builtin_amdgcn_s_setprio(1);
#pragma unroll
        for (int ks = 0; ks < 2; ks++) {
#pragma unroll
            for (int ni = 0; ni < 4; ni++) {
                bf16x8 kf = *(const bf16x8*)&Ks[ni * 16 + fr][ks * 32 + fk];
                sc[ni] = __builtin_amdgcn_mfma_f32_16x16x32_bf16(qf[ks], kf, sc[ni], 0, 0, 0);
            }
        }
        __builtin_amdgcn_s_setprio(0);

        // ---- scale to log2 domain + causal mask ----
        float p[4][4];
#pragma unroll
        for (int ni = 0; ni < 4; ni++) {
            const int key = k0 + ni * 16 + fr;
#pragma unroll
            for (int j = 0; j < 4; j++) {
                const int qg = q0 + w * 16 + fg * 4 + j;
                p[ni][j] = (key <= qg) ? sc[ni][j] * C_LOG2 : -1e30f;
            }
        }

        // ---- online softmax (exp2 domain), defer-max (T13) ----
#pragma unroll
        for (int j = 0; j < 4; j++) {
            float rmax = fmaxf(fmaxf(p[0][j], p[1][j]), fmaxf(p[2][j], p[3][j]));
#pragma unroll
            for (int d = 1; d < 16; d <<= 1) rmax = fmaxf(rmax, __shfl_xor(rmax, d));
            if (rmax > m_r[j] + 8.f) {         // rescale only on real growth
                float scale = exp2f(m_r[j] - rmax);
                l_r[j] *= scale;
#pragma unroll
                for (int nc = 0; nc < 4; nc++) o[nc][j] *= scale;
                m_r[j] = rmax;
            }
            float rsum = 0.f;
#pragma unroll
            for (int ni = 0; ni < 4; ni++) {
                float e = exp2f(p[ni][j] - m_r[j]);   // bounded by 2^8
                p[ni][j] = e; rsum += e;
            }
#pragma unroll
            for (int d = 1; d < 16; d <<= 1) rsum += __shfl_xor(rsum, d);
            l_r[j] += rsum;
        }

        // ---- P -> A-layout via per-wave LDS bounce ----
#pragma unroll
        for (int ni = 0; ni < 4; ni++)
#pragma unroll
            for (int j = 0; j < 4; j++)
                Ps[w][fg * 4 + j][ni * 16 + fr] = (bf16_t)p[ni][j];

        // ---- PV ----
        __builtin_amdgcn_s_setprio(1);
#pragma unroll
        for (int ks = 0; ks < 2; ks++) {
            bf16x8 pa = *(const bf16x8*)&Ps[w][fr][ks * 32 + fk];
#pragma unroll
            for (int nc = 0; nc < 4; nc++) {
                bf16x8 vf = *(const bf16x8*)&Vs[nc * 16 + fr][ks * 32 + fk];
                o[nc] = __builtin_amdgcn_mfma_f32_16x16x32_bf16(pa, vf, o[nc], 0, 0, 0);
            }
        }
        __builtin_amdgcn_s_setprio(0);
    }

    // ---- epilogue ----
#pragma unroll
    for (int j = 0; j < 4; j++) {
        const float inv = 1.f / l_r[j];
        const int q = q0 + w * 16 + fg * 4 + j;
        bf16_t* op = O + (size_t)(b * S_LEN + q) * D_DIM + h * DH;
#pragma unroll
        for (int nc = 0; nc < 4; nc++)
            op[nc * 16 + fr] = (bf16_t)(o[nc][j] * inv);
    }
}

// ---------------------------------------------------------------------------
extern "C" void kernel_launch(void* const* d_in, const int* in_sizes, int n_in,
                              void* d_out, int out_size, void* d_ws, size_t ws_size,
                              hipStream_t stream)
{
    const float* x      = (const float*)d_in[0];
    const float* fqk_wQ = (const float*)d_in[1];
    const float* fqk_wK = (const float*)d_in[2];
    const float* fv_w   = (const float*)d_in[3];
    const float* rqk_wQ = (const float*)d_in[4];
    const float* rqk_wK = (const float*)d_in[5];
    const float* rv_w   = (const float*)d_in[6];
    const float* fkn_w  = (const float*)d_in[7];
    const float* rkn_w  = (const float*)d_in[8];
    const float* f_qk   = (const float*)d_in[9];
    const float* f_v    = (const float*)d_in[10];
    const float* r_qk   = (const float*)d_in[11];
    const float* r_v    = (const float*)d_in[12];
    const float* f_know = (const float*)d_in[13];
    const float* r_know = (const float*)d_in[14];
    const float* W_O    = (const float*)d_in[15];
    const float* ln1g   = (const float*)d_in[16];
    const float* ln1b   = (const float*)d_in[17];
    const float* ln2g   = (const float*)d_in[18];
    const float* ln2b   = (const float*)d_in[19];
    float* out_f = (float*)d_out;
    (void)ws_size; (void)in_sizes; (void)n_in; (void)out_size;

    // ---- workspace layout (reused slots) ----
    char* ws = (char*)d_ws;
    const size_t MB = 1024 * 1024;
    bf16_t* rqkT   = (bf16_t*)(ws + 0 * MB);    // [1024][2048]  4MB
    bf16_t* rvT    = (bf16_t*)(ws + 4 * MB);    // [1024][2048]  4MB
    bf16_t* rknT   = (bf16_t*)(ws + 8 * MB);    // [1024][1024]  2MB
    bf16_t* woB    = (bf16_t*)(ws + 10 * MB);   // [1024][1024]  2MB
    bf16_t* fknT   = (bf16_t*)(ws + 12 * MB);   // [1024][1024]  2MB
    bf16_t* buf_nx = (bf16_t*)(ws + 14 * MB);   // 8MB: nx -> Vt -> nx2
    bf16_t* buf_y  = (bf16_t*)(ws + 22 * MB);   // 32MB: y[4096][4096] -> QKV[12288][1024]
    char*   buf_s  = ws + 54 * MB;              // 48MB
    bf16_t* fqkT   = (bf16_t*)(buf_s);               // [2048][1024] 4MB (pre-ws only)
    bf16_t* fvT    = (bf16_t*)(buf_s + 4 * MB);      // contiguous -> N=4096 B
    bf16_t* s_q    = (bf16_t*)(buf_s);               // [12288][2048] grouped A
    bf16_t* s_k    = (bf16_t*)(buf_s) + (size_t)4096 * 2048;
    bf16_t* s_v    = (bf16_t*)(buf_s) + (size_t)8192 * 2048;
    bf16_t* attn   = (bf16_t*)(buf_s);               // [4096][1024] 8MB
    float*  P0     = (float*)(buf_s + 16 * MB);      // W_O split-K partials 2x16MB
    float*  P0k    = (float*)(buf_s);                // know split-K partials
    float*  P1k    = (float*)(buf_s + 16 * MB);
    bf16_t* sk2    = (bf16_t*)(buf_s + 32 * MB);     // [4096][1024] 8MB
    bf16_t* Qb     = buf_y;                          // QKV contiguous [12288][1024]
    bf16_t* Kb     = buf_y + (size_t)4096 * 1024;
    bf16_t* Vb     = buf_y + (size_t)8192 * 1024;
    bf16_t* Vt     = buf_nx;                         // [2][1024][2048]

    const dim3 blk256(256), blkT(32, 8);

    // ---- weight conversion ----
    tcast_kernel<<<dim3(R_DIM / 32, D_DIM / 32, N_NEU), blkT, 0, stream>>>(f_qk, fqkT, D_DIM, R_DIM);
    tcast_kernel<<<dim3(R_DIM / 32, D_DIM / 32, N_NEU), blkT, 0, stream>>>(f_v, fvT, D_DIM, R_DIM);
    tcast_kernel<<<dim3(KR_DIM / 32, D_DIM / 32, N_NEU), blkT, 0, stream>>>(f_know, fknT, D_DIM, KR_DIM);
    tcast_kernel<<<dim3(D_DIM / 32, 2048 / 32, 1), blkT, 0, stream>>>(r_qk, rqkT, 2048, D_DIM);
    tcast_kernel<<<dim3(D_DIM / 32, 2048 / 32, 1), blkT, 0, stream>>>(r_v, rvT, 2048, D_DIM);
    tcast_kernel<<<dim3(D_DIM / 32, 1024 / 32, 1), blkT, 0, stream>>>(r_know, rknT, 1024, D_DIM);
    cast_kernel<<<dim3(1024 * 1024 / 4 / 256), blk256, 0, stream>>>(W_O, woB, 1024 * 1024 / 4);

    // ---- LN1 ----
    ln_kernel<<<dim3(ROWS), blk256, 0, stream>>>(x, ln1g, ln1b, buf_nx);

    // ---- fused feature GEMM: y[4096][4096] = nx @ [fqkT;fvT]^T ----
    gemm_kernel<0><<<dim3(32, 32), blk256, 0, stream>>>(buf_nx, fqkT, fqkT, 1 << 30, buf_y, nullptr, 4096, 4096, 1024);

    // ---- fused weighted sums -> sq|sk|sv [12288][2048] ----
    wsf_kernel<<<dim3(ROWS), blk256, 0, stream>>>(buf_y, fqk_wQ, rqk_wQ, fqk_wK, rqk_wK, fv_w, rv_w, s_q, s_k, s_v);

    // ---- grouped restore GEMM: QKV[12288][1024] (768 blocks, B-select) ----
    gemm_kernel<0><<<dim3(8, 96), blk256, 0, stream>>>((bf16_t*)buf_s, rqkT, rvT, 64, buf_y, nullptr, 12288, 1024, 2048);

    // ---- V -> Vt ----
    tbf_kernel<<<dim3(D_DIM / 32, S_LEN / 32, B_DIM), blkT, 0, stream>>>(Vb, Vt, S_LEN, D_DIM);

    // ---- attention (1024 blocks, 1D grid, balanced mapping) ----
    fa_kernel<<<dim3(1024), blk256, 0, stream>>>(Qb, Kb, Vt, attn);

    // ---- W_O split-K=2: partials P0/P1 (512 blocks) ----
    gemm_kernel<2><<<dim3(8, 32, 2), blk256, 0, stream>>>(attn, woB, woB, 1 << 30, P0, nullptr, 4096, 1024, 1024);

    // ---- LN2 fused: d_out = x + P0 + P1; nx2 = LN(d_out) ----
    ln2x_kernel<<<dim3(ROWS), blk256, 0, stream>>>(x, P0, P0 + (size_t)4096 * 1024, ln2g, ln2b, out_f, buf_nx);

    // ---- know feature split-K=2: partials P0k/P1k (512 blocks) ----
    gemm_kernel<2><<<dim3(8, 32, 2), blk256, 0, stream>>>(buf_nx, fknT, fknT, 1 << 30, P0k, nullptr, 4096, 1024, 1024);

    // ---- know ws (fused reduce) -> sk2 ----
    ws2_kernel<<<dim3(ROWS / 2), blk256, 0, stream>>>(P0k, P1k, fkn_w, rkn_w, sk2);

    // ---- out = sk2 @ rknT^T + x2 -> d_out ----
    gemm_kernel<1><<<dim3(8, 32), blk256, 0, stream>>>(sk2, rknT, rknT, 1 << 30, d_out, out_f, 4096, 1024, 1024);
}